// Round 2
// baseline (232.267 us; speedup 1.0000x reference)
//
#include <hip/hip_runtime.h>

#define EPS   1e-5f
#define SLOPE 0.01f

// ---------------------------------------------------------------------------
// Workspace layout (float offsets). Total 20,287,424 floats = 81.1 MB.
// ---------------------------------------------------------------------------
#define WS_H1B  0L            // h1  bf16 NHWC (64,56,56,96)   (9633792 f)
#define WS_OFF  9633792L      // off f32 [n=12544][32]            401408
#define WS_S1   10035200L     // bn1 scale f32 [96]
#define WS_T1   10035296L     // bn1 bias  f32 [96]
#define WS_T2   10035392L     // fused dcn_b+bn2 bias f32 [768]
#define WS_SB   10036160L     // S   bf16 [n=12544][k=1536]    (9633792 f)
#define WS_WTB  19669952L     // Wtb bf16 [oc=768][k=1536]      (589824 f)
#define WS_WOB  20259776L     // Wob bf16 [oc=32][k=1536]        (24576 f)
#define WS_W1B  20284352L     // W1b bf16 [ks=2][oc=96][kl=32]    (3072 f)

__device__ __forceinline__ unsigned short f2bf(float f) {
    unsigned int u = __builtin_bit_cast(unsigned int, f);
    u += 0x7fffu + ((u >> 16) & 1u);
    return (unsigned short)(u >> 16);
}
__device__ __forceinline__ float bf2f(unsigned short u) {
    unsigned int t = ((unsigned int)u) << 16;
    return __builtin_bit_cast(float, t);
}

typedef __attribute__((ext_vector_type(4))) unsigned short ushort4v;
typedef __attribute__((ext_vector_type(8))) unsigned short ushort8v;
typedef __attribute__((ext_vector_type(8))) short bf16x8;
typedef __attribute__((ext_vector_type(4))) float floatx4;

// ---------------------------------------------------------------------------
// K0: weight prep, transpose-via-LDS for coalescing.
// ---------------------------------------------------------------------------
__global__ __launch_bounds__(256) void k0_prep(
    const float* __restrict__ stem_w, const float* __restrict__ stem_b,
    const float* __restrict__ bn1_g,  const float* __restrict__ bn1_b,
    const float* __restrict__ bn1_m,  const float* __restrict__ bn1_v,
    const float* __restrict__ off_w,  const float* __restrict__ dcn_w,
    const float* __restrict__ dcn_b,  const float* __restrict__ bn2_g,
    const float* __restrict__ bn2_b,  const float* __restrict__ bn2_m,
    const float* __restrict__ bn2_v,  float* __restrict__ ws)
{
    const int tid = threadIdx.x;
    const int blk = blockIdx.x;
    unsigned short* Wtb = (unsigned short*)(ws + WS_WTB);
    unsigned short* Wob = (unsigned short*)(ws + WS_WOB);
    unsigned short* W1b = (unsigned short*)(ws + WS_W1B);

    if (blk < 800) {
        __shared__ float row[1536];
        const int oc = (blk < 768) ? blk : blk - 768;
        const float* src = (blk < 768) ? (dcn_w + (long)oc * 1536)
                                       : (off_w + (long)oc * 1536);
        for (int i = tid; i < 1536; i += 256) row[i] = src[i];
        float sc = 1.f;
        if (blk < 768) sc = bn2_g[oc] * rsqrtf(bn2_v[oc] + EPS);
        __syncthreads();
        if (tid < 192) {
            int k0 = tid * 8;
            ushort8v o;
#pragma unroll
            for (int t = 0; t < 8; t++) {
                int k = k0 + t;
                int kk = k / 96, c = k % 96;      // k = kk*96 + c
                ((unsigned short*)&o)[t] = f2bf(row[c * 16 + kk] * sc);
            }
            unsigned short* dst = (blk < 768) ? (Wtb + (long)oc * 1536 + k0)
                                              : (Wob + (long)oc * 1536 + k0);
            *(ushort8v*)dst = o;
        }
    } else {
        for (int i = tid; i < 6144; i += 256) {
            int ks = i / 3072, rr = i % 3072;
            int oc = rr >> 5, kl = rr & 31;
            int k = ks * 32 + kl;
            W1b[i] = f2bf(k < 48 ? stem_w[oc * 48 + k] : 0.f);
        }
        if (tid < 96) {
            float s = bn1_g[tid] * rsqrtf(bn1_v[tid] + EPS);
            ws[WS_S1 + tid] = s;
            ws[WS_T1 + tid] = stem_b[tid] * s + bn1_b[tid] - bn1_m[tid] * s;
        }
        for (int i = tid; i < 768; i += 256) {
            float inv2 = bn2_g[i] * rsqrtf(bn2_v[i] + EPS);
            ws[WS_T2 + i] = dcn_b[i] * inv2 + bn2_b[i] - bn2_m[i] * inv2;
        }
    }
}

// ---------------------------------------------------------------------------
// K1: stem conv as bf16 MFMA GEMM, coalesced staging + LDS-repacked stores.
// ---------------------------------------------------------------------------
__global__ __launch_bounds__(256) void k1_stem_mfma(
    const float* __restrict__ x, const unsigned short* __restrict__ W1b,
    const float* __restrict__ s1, const float* __restrict__ t1,
    unsigned short* __restrict__ h1)
{
    const int tid  = threadIdx.x;
    const int wave = tid >> 6, lane = tid & 63;
    const int m = lane & 15, quad = lane >> 4;
    const int p0 = blockIdx.x * 128;

    __shared__ unsigned short sm[14336];   // 28672 B
    unsigned short* sA = sm;               // [2][128][32]
    unsigned short* sB = sm + 8192;        // [2][96][32]

#pragma unroll
    for (int i = 0; i < 3; i++) {
        int inst = wave * 3 + i;
        const unsigned short* g = W1b + inst * 512 + lane * 8;
        __builtin_amdgcn_global_load_lds(
            (const __attribute__((address_space(1))) void*)g,
            (__attribute__((address_space(3))) void*)(sB + inst * 512), 16, 0, 0);
    }
    {
        int r = tid >> 1, off = 16 + (tid & 1) * 8;
        *(ushort8v*)&sA[4096 + r * 32 + off] = (ushort8v)0;
    }
#pragma unroll
    for (int i = 0; i < 6; i++) {
        int unit = i * 256 + tid;
        int r = unit & 127, s = unit >> 7;
        int ci = s >> 2, kh = s & 3;
        int p = p0 + r;
        int b = p / 3136, rem = p % 3136;
        int oy = rem / 56, ox = rem % 56;
        float4 v = *(const float4*)&x[((long)((b * 3 + ci) * 224 + oy * 4 + kh)) * 224 + ox * 4];
        ushort4v hv;
        hv.x = f2bf(v.x); hv.y = f2bf(v.y); hv.z = f2bf(v.z); hv.w = f2bf(v.w);
        int k0i = ci * 16 + kh * 4;
        *(ushort4v*)&sA[(k0i >> 5) * 4096 + r * 32 + (k0i & 31)] = hv;
    }
    __syncthreads();

    bf16x8 bfv[6][2], af[2][2];
#pragma unroll
    for (int j = 0; j < 6; j++)
#pragma unroll
        for (int ks = 0; ks < 2; ks++)
            bfv[j][ks] = *(const bf16x8*)&sB[ks * 3072 + (j * 16 + m) * 32 + quad * 8];
#pragma unroll
    for (int rt = 0; rt < 2; rt++)
#pragma unroll
        for (int ks = 0; ks < 2; ks++)
            af[rt][ks] = *(const bf16x8*)&sA[ks * 4096 + (wave * 32 + rt * 16 + m) * 32 + quad * 8];

    floatx4 acc[2][6];
#pragma unroll
    for (int rt = 0; rt < 2; rt++)
#pragma unroll
        for (int j = 0; j < 6; j++) {
            floatx4 a = (floatx4)0.f;
            a = __builtin_amdgcn_mfma_f32_16x16x32_bf16(af[rt][0], bfv[j][0], a, 0, 0, 0);
            a = __builtin_amdgcn_mfma_f32_16x16x32_bf16(af[rt][1], bfv[j][1], a, 0, 0, 0);
            acc[rt][j] = a;
        }

    __syncthreads();
#pragma unroll
    for (int j = 0; j < 6; j++) {
        int c = j * 16 + m;
        float sc = s1[c], bi = t1[c];
#pragma unroll
        for (int rt = 0; rt < 2; rt++)
#pragma unroll
            for (int r = 0; r < 4; r++) {
                int row = wave * 32 + rt * 16 + quad * 4 + r;
                float v = acc[rt][j][r] * sc + bi;
                v = v >= 0.f ? v : SLOPE * v;
                sm[row * 96 + c] = f2bf(v);
            }
    }
    __syncthreads();
#pragma unroll
    for (int i = 0; i < 6; i++) {
        int idx = (i * 256 + tid) * 8;
        *(ushort8v*)&h1[(long)p0 * 96 + idx] = *(const ushort8v*)&sm[idx];
    }
}

// ---------------------------------------------------------------------------
// K2: offset conv, K-split x4 across blocks + dbuf prefetch + atomic reduce.
// Block bx: nt = bx%98, ks = bx/98 handles k in [ks*384, ks*384+384).
// off must be memset to 0 beforehand; ks==0 partial adds off_b.
// ---------------------------------------------------------------------------
__global__ __launch_bounds__(256) void k2_mfma(
    const unsigned short* __restrict__ h1,   // bf16 NHWC
    const unsigned short* __restrict__ Wob,  // [32][1536] bf16
    const float* __restrict__ off_b, float* __restrict__ off)
{
    const int tid  = threadIdx.x;
    const int wave = tid >> 6, lane = tid & 63;
    const int m = lane & 15, quad = lane >> 4;
    const int nt = blockIdx.x % 98, ks = blockIdx.x / 98;
    const int n0 = nt * 128;

    __shared__ unsigned short sA[2][4096];   // [buf][128*32]
    __shared__ unsigned short sB[2][1024];   // [buf][32*32]

    const int skoff = (lane & 3) * 8;
    int n_a = n0 + wave * 32 + (lane >> 2);
    int n_b = n_a + 16;
    int ba = n_a / 196, pa = n_a % 196;
    int bb = n_b / 196, pb = n_b % 196;
    long pixa = ((long)(ba * 56 + (pa / 14) * 4) * 56 + (pa % 14) * 4);
    long pixb = ((long)(bb * 56 + (pb / 14) * 4) * 56 + (pb % 14) * 4);

    const unsigned short* gB = Wob + (long)(wave * 16 + (lane >> 2)) * 1536 + ks * 384 + skoff;
    const int lofA0 = (wave * 32) * 32;
    const int lofA1 = (wave * 32 + 16) * 32;
    const int lofB  = (wave * 16) * 32;

    auto issue = [&](int buf, int kt) {
        int khw = ks * 4 + kt / 3;
        int c0  = (kt % 3) * 32;
        int kh  = khw >> 2, kw = khw & 3;
        long eoff = (long)(kh * 56 + kw) * 96 + c0 + skoff;
        __builtin_amdgcn_global_load_lds(
            (const __attribute__((address_space(1))) void*)(h1 + pixa * 96 + eoff),
            (__attribute__((address_space(3))) void*)&sA[buf][lofA0], 16, 0, 0);
        __builtin_amdgcn_global_load_lds(
            (const __attribute__((address_space(1))) void*)(h1 + pixb * 96 + eoff),
            (__attribute__((address_space(3))) void*)&sA[buf][lofA1], 16, 0, 0);
        if (wave < 2)
            __builtin_amdgcn_global_load_lds(
                (const __attribute__((address_space(1))) void*)(gB + kt * 32),
                (__attribute__((address_space(3))) void*)&sB[buf][lofB], 16, 0, 0);
    };

    floatx4 acc[2][2];
#pragma unroll
    for (int i = 0; i < 2; i++)
#pragma unroll
        for (int j = 0; j < 2; j++) acc[i][j] = (floatx4)0.f;

    issue(0, 0);
    for (int kt = 0; kt < 12; ++kt) {
        __syncthreads();                       // drains tile kt's loads
        if (kt < 11) issue((kt + 1) & 1, kt + 1);
        const unsigned short* bufA = sA[kt & 1];
        const unsigned short* bufB = sB[kt & 1];
        bf16x8 af[2], bfr[2];
#pragma unroll
        for (int i = 0; i < 2; i++)
            af[i] = *(const bf16x8*)&bufA[(wave * 32 + i * 16 + m) * 32 + quad * 8];
#pragma unroll
        for (int j = 0; j < 2; j++)
            bfr[j] = *(const bf16x8*)&bufB[(j * 16 + m) * 32 + quad * 8];
#pragma unroll
        for (int i = 0; i < 2; i++)
#pragma unroll
            for (int j = 0; j < 2; j++)
                acc[i][j] = __builtin_amdgcn_mfma_f32_16x16x32_bf16(
                    af[i], bfr[j], acc[i][j], 0, 0, 0);
    }

    float tb[2];
#pragma unroll
    for (int j = 0; j < 2; j++) tb[j] = (ks == 0) ? off_b[j * 16 + m] : 0.f;
#pragma unroll
    for (int i = 0; i < 2; i++)
#pragma unroll
        for (int r = 0; r < 4; r++) {
            long n = n0 + wave * 32 + i * 16 + quad * 4 + r;
#pragma unroll
            for (int j = 0; j < 2; j++)
                atomicAdd(&off[n * 32 + j * 16 + m], acc[i][j][r] + tb[j]);
        }
}

// ---------------------------------------------------------------------------
// K3: bilinear sampling from bf16 h1 -> S bf16 [n][k], k = kk*96 + c.
// ---------------------------------------------------------------------------
__global__ __launch_bounds__(384) void k3_sample(
    const unsigned short* __restrict__ h1, const float* __restrict__ off,
    unsigned short* __restrict__ S)
{
    const int p = blockIdx.x;     // 0..195
    const int b = blockIdx.y;     // 0..63
    const int y = p / 14, xo = p % 14;
    const int tid = threadIdx.x;
    const int c4 = tid % 24, kk = tid / 24;
    const int kh = kk >> 2, kw = kk & 3;

    const float* ob = off + ((long)(b * 196 + p)) * 32;
    float dy = ob[kk * 2];
    float dx = ob[kk * 2 + 1];

    float py = (float)(y * 4 + kh) + dy;
    float px = (float)(xo * 4 + kw) + dx;
    float y0f = floorf(py), x0f = floorf(px);
    float wy = py - y0f, wx = px - x0f;
    int y0 = (int)y0f, x0 = (int)x0f;
    int y1 = y0 + 1,  x1 = x0 + 1;

    float my0 = (y0 >= 0 && y0 < 56) ? 1.f : 0.f;
    float my1 = (y1 >= 0 && y1 < 56) ? 1.f : 0.f;
    float mx0 = (x0 >= 0 && x0 < 56) ? 1.f : 0.f;
    float mx1 = (x1 >= 0 && x1 < 56) ? 1.f : 0.f;
    int y0c = min(max(y0, 0), 55), y1c = min(max(y1, 0), 55);
    int x0c = min(max(x0, 0), 55), x1c = min(max(x1, 0), 55);

    const unsigned short* hb = h1 + (long)b * 56 * 56 * 96 + c4 * 4;
    ushort4v v00 = *(const ushort4v*)&hb[(y0c * 56 + x0c) * 96];
    ushort4v v01 = *(const ushort4v*)&hb[(y0c * 56 + x1c) * 96];
    ushort4v v10 = *(const ushort4v*)&hb[(y1c * 56 + x0c) * 96];
    ushort4v v11 = *(const ushort4v*)&hb[(y1c * 56 + x1c) * 96];

    float w00 = my0 * mx0 * (1.f - wy) * (1.f - wx);
    float w01 = my0 * mx1 * (1.f - wy) * wx;
    float w10 = my1 * mx0 * wy * (1.f - wx);
    float w11 = my1 * mx1 * wy * wx;

    ushort4v rr;
#pragma unroll
    for (int c = 0; c < 4; c++) {
        float v = bf2f(((unsigned short*)&v00)[c]) * w00
                + bf2f(((unsigned short*)&v01)[c]) * w01
                + bf2f(((unsigned short*)&v10)[c]) * w10
                + bf2f(((unsigned short*)&v11)[c]) * w11;
        ((unsigned short*)&rr)[c] = f2bf(v);
    }

    long n = (long)b * 196 + p;
    *(ushort4v*)&S[n * 1536 + kk * 96 + c4 * 4] = rr;
}

// ---------------------------------------------------------------------------
// K4: bf16 MFMA GEMM  C[n][oc] = S[n][k] * Wtb[oc][k]^T  (N=12544,M=768,K=1536)
// 128n x 64oc tile, BK=64, 24 K-steps.
// COUNTED-VMCNT PIPELINE (T3/T4): 3 LDS buffers, prefetch depth 2.
//   prologue: issue tiles 0,1 (12 loads in flight)
//   step kt:  s_waitcnt vmcnt(6)   <- tile kt landed, kt+1 stays in flight
//             s_barrier (raw - no implicit vmcnt(0) drain, unlike __syncthreads)
//             issue tile kt+2      <- into the buffer read at step kt-1, which
//                                     every wave finished before this barrier
//             ds_read buf[kt%3] + 16 MFMA
// Tile kt is waited on ~2 compute-steps after issue -> load latency hidden.
// LDS 72KB (3 bufs) -> 2 blocks/CU (matches measured 24% occupancy anyway).
// Rows are 128B -> XOR-swizzle slot^=(row&7) keeps ds_read conflict-free
// (verified: SQ_LDS_BANK_CONFLICT == 0); global_load_lds dest linear, the
// SOURCE k-offset is pre-swizzled per-lane, reads apply the same XOR.
// 1176 blocks, XCD swizzle: each XCD gets 147 consecutive works.
// ---------------------------------------------------------------------------
__global__ __launch_bounds__(256) void k4_gemm_mfma(
    const unsigned short* __restrict__ S,    // [12544][1536] bf16
    const unsigned short* __restrict__ Wtb,  // [768][1536]  bf16 (B^T, scaled)
    const float* __restrict__ t2, float* __restrict__ out)
{
    const int tid  = threadIdx.x;
    const int wave = tid >> 6, lane = tid & 63;

    // swizzle: 1176 works = 8 XCDs x 147 consecutive works
    int lid = blockIdx.x;
    int work = (lid & 7) * 147 + (lid >> 3);
    const int n0  = (work / 12) * 128;
    const int oc0 = (work % 12) * 64;

    const int wr = wave >> 1, wc = wave & 1;
    const int m = lane & 15, quad = lane >> 4;

    __shared__ unsigned short sA[3][8192];   // [buf][128 rows * 64 k] 48KB
    __shared__ unsigned short sB[3][4096];   // [buf][ 64 rows * 64 k] 24KB

    // staging geometry: one global_load_lds = 64 lanes x 16B = 8 rows of 128B.
    // lane -> row lr = lane>>3, 16B slot ls = lane&7.
    // LDS slot s of row r holds logical k-chunk s ^ (r&7); source fetches
    // chunk ls^lr (r&7 == lr since all row bases are multiples of 8).
    const int lr = lane >> 3;
    const int ls = lane & 7;
    const int swzk = ((ls ^ lr) * 8);        // element offset within 64-k row

    const unsigned short* gA[4];
    const unsigned short* gB[2];
#pragma unroll
    for (int t = 0; t < 4; t++)
        gA[t] = S + (long)(n0 + wave * 32 + t * 8 + lr) * 1536 + swzk;
#pragma unroll
    for (int t = 0; t < 2; t++)
        gB[t] = Wtb + (long)(oc0 + wave * 16 + t * 8 + lr) * 1536 + swzk;

    auto issue = [&](int buf) {
#pragma unroll
        for (int t = 0; t < 4; t++) {
            __builtin_amdgcn_global_load_lds(
                (const __attribute__((address_space(1))) void*)gA[t],
                (__attribute__((address_space(3))) void*)&sA[buf][(wave * 32 + t * 8) * 64],
                16, 0, 0);
            gA[t] += 64;
        }
#pragma unroll
        for (int t = 0; t < 2; t++) {
            __builtin_amdgcn_global_load_lds(
                (const __attribute__((address_space(1))) void*)gB[t],
                (__attribute__((address_space(3))) void*)&sB[buf][(wave * 16 + t * 8) * 64],
                16, 0, 0);
            gB[t] += 64;
        }
    };

    floatx4 acc[4][2];
#pragma unroll
    for (int i = 0; i < 4; i++)
#pragma unroll
        for (int j = 0; j < 2; j++) acc[i][j] = (floatx4)0.f;

    auto compute = [&](int cur) {
        const unsigned short* bufA = sA[cur];
        const unsigned short* bufB = sB[cur];
        // read swizzle: logical 16B-chunk (ks*4+quad) of row r lives at
        // slot (ks*4+quad)^(r&7); r&7 == m&7 for all fragment rows.
        bf16x8 af[4][2], bfr[2][2];
#pragma unroll
        for (int i = 0; i < 4; i++)
#pragma unroll
            for (int ks = 0; ks < 2; ks++)
                af[i][ks] = *(const bf16x8*)&bufA[(wr * 64 + i * 16 + m) * 64
                                                 + (((ks * 4 + quad) ^ (m & 7)) * 8)];
#pragma unroll
        for (int j = 0; j < 2; j++)
#pragma unroll
            for (int ks = 0; ks < 2; ks++)
                bfr[j][ks] = *(const bf16x8*)&bufB[(wc * 32 + j * 16 + m) * 64
                                                  + (((ks * 4 + quad) ^ (m & 7)) * 8)];
#pragma unroll
        for (int i = 0; i < 4; i++)
#pragma unroll
            for (int j = 0; j < 2; j++) {
                acc[i][j] = __builtin_amdgcn_mfma_f32_16x16x32_bf16(
                    af[i][0], bfr[j][0], acc[i][j], 0, 0, 0);
                acc[i][j] = __builtin_amdgcn_mfma_f32_16x16x32_bf16(
                    af[i][1], bfr[j][1], acc[i][j], 0, 0, 0);
            }
    };

    issue(0);
    issue(1);                                 // 12 loads in flight
    int cur = 0;
    for (int kt = 0; kt < 23; ++kt) {
        // tile kt's 6 loads are the oldest; leave the newer 6 (tile kt+1)
        // in flight across the barrier. In-order VMEM retirement makes
        // vmcnt(6) == "tile kt fully landed".
        asm volatile("s_waitcnt vmcnt(6)" ::: "memory");
        __builtin_amdgcn_s_barrier();         // raw barrier: no vmcnt(0) drain
        if (kt < 22) {
            int nb = cur + 2; if (nb >= 3) nb -= 3;
            issue(nb);                        // overwrites buf read at kt-1
        }
        compute(cur);
        cur = (cur == 2) ? 0 : cur + 1;
    }
    asm volatile("s_waitcnt vmcnt(0)" ::: "memory");  // tail: tile 23
    __builtin_amdgcn_s_barrier();
    compute(cur);

    float tb[2];
#pragma unroll
    for (int j = 0; j < 2; j++) tb[j] = t2[oc0 + wc * 32 + j * 16 + m];
#pragma unroll
    for (int i = 0; i < 4; i++) {
#pragma unroll
        for (int r = 0; r < 4; r++) {
            long n = n0 + wr * 64 + i * 16 + quad * 4 + r;
            float* orow = out + n * 768 + oc0 + wc * 32 + m;
#pragma unroll
            for (int j = 0; j < 2; j++) {
                float v = acc[i][j][r] + tb[j];
                orow[j * 16] = v >= 0.f ? v : SLOPE * v;
            }
        }
    }
}

// ---------------------------------------------------------------------------
extern "C" void kernel_launch(void* const* d_in, const int* in_sizes, int n_in,
                              void* d_out, int out_size, void* d_ws, size_t ws_size,
                              hipStream_t stream)
{
    const float* x      = (const float*)d_in[0];
    const float* stem_w = (const float*)d_in[1];
    const float* stem_b = (const float*)d_in[2];
    const float* bn1_g  = (const float*)d_in[3];
    const float* bn1_b  = (const float*)d_in[4];
    const float* bn1_m  = (const float*)d_in[5];
    const float* bn1_v  = (const float*)d_in[6];
    const float* off_w  = (const float*)d_in[7];
    const float* off_b  = (const float*)d_in[8];
    const float* dcn_w  = (const float*)d_in[9];
    const float* dcn_b  = (const float*)d_in[10];
    const float* bn2_g  = (const float*)d_in[11];
    const float* bn2_b  = (const float*)d_in[12];
    const float* bn2_m  = (const float*)d_in[13];
    const float* bn2_v  = (const float*)d_in[14];

    float* ws  = (float*)d_ws;        // needs 81.2 MB
    float* out = (float*)d_out;

    unsigned short* h1  = (unsigned short*)(ws + WS_H1B);
    float* off = ws + WS_OFF;
    float* s1  = ws + WS_S1;
    float* t1  = ws + WS_T1;
    float* t2  = ws + WS_T2;
    unsigned short* Sb  = (unsigned short*)(ws + WS_SB);
    unsigned short* Wtb = (unsigned short*)(ws + WS_WTB);
    unsigned short* Wob = (unsigned short*)(ws + WS_WOB);
    unsigned short* W1b = (unsigned short*)(ws + WS_W1B);

    k0_prep<<<801, 256, 0, stream>>>(stem_w, stem_b, bn1_g, bn1_b, bn1_m, bn1_v,
                                     off_w, dcn_w, dcn_b, bn2_g, bn2_b, bn2_m,
                                     bn2_v, ws);
    // zero the atomic-accumulated offset buffer (re-poisoned 0xAA each launch)
    hipMemsetAsync(off, 0, 401408 * sizeof(float), stream);
    k1_stem_mfma<<<1568, 256, 0, stream>>>(x, W1b, s1, t1, h1);
    k2_mfma<<<392, 256, 0, stream>>>(h1, Wob, off_b, off);
    k3_sample<<<dim3(196, 64), 384, 0, stream>>>(h1, off, Sb);
    k4_gemm_mfma<<<1176, 256, 0, stream>>>(Sb, Wtb, t2, out);
}

// Round 3
// 217.235 us; speedup vs baseline: 1.0692x; 1.0692x over previous
//
#include <hip/hip_runtime.h>

#define EPS   1e-5f
#define SLOPE 0.01f

// ---------------------------------------------------------------------------
// Workspace layout (float offsets). Total 20,287,424 floats = 81.1 MB.
// ---------------------------------------------------------------------------
#define WS_H1B  0L            // h1  bf16 NHWC (64,56,56,96)   (9633792 f)
#define WS_OFF  9633792L      // off f32 [n=12544][32]            401408
#define WS_S1   10035200L     // bn1 scale f32 [96]
#define WS_T1   10035296L     // bn1 bias  f32 [96]
#define WS_T2   10035392L     // fused dcn_b+bn2 bias f32 [768]
#define WS_SB   10036160L     // S   bf16 [n=12544][k=1536]    (9633792 f)
#define WS_WTB  19669952L     // Wtb bf16 [oc=768][k=1536]      (589824 f)
#define WS_WOB  20259776L     // Wob bf16 [oc=32][k=1536]        (24576 f)
#define WS_W1B  20284352L     // W1b bf16 [ks=2][oc=96][kl=32]    (3072 f)

__device__ __forceinline__ unsigned short f2bf(float f) {
    unsigned int u = __builtin_bit_cast(unsigned int, f);
    u += 0x7fffu + ((u >> 16) & 1u);
    return (unsigned short)(u >> 16);
}
__device__ __forceinline__ float bf2f(unsigned short u) {
    unsigned int t = ((unsigned int)u) << 16;
    return __builtin_bit_cast(float, t);
}

typedef __attribute__((ext_vector_type(4))) unsigned short ushort4v;
typedef __attribute__((ext_vector_type(8))) unsigned short ushort8v;
typedef __attribute__((ext_vector_type(8))) short bf16x8;
typedef __attribute__((ext_vector_type(4))) float floatx4;

// ---------------------------------------------------------------------------
// K0: weight prep, transpose-via-LDS for coalescing.
// ---------------------------------------------------------------------------
__global__ __launch_bounds__(256) void k0_prep(
    const float* __restrict__ stem_w, const float* __restrict__ stem_b,
    const float* __restrict__ bn1_g,  const float* __restrict__ bn1_b,
    const float* __restrict__ bn1_m,  const float* __restrict__ bn1_v,
    const float* __restrict__ off_w,  const float* __restrict__ dcn_w,
    const float* __restrict__ dcn_b,  const float* __restrict__ bn2_g,
    const float* __restrict__ bn2_b,  const float* __restrict__ bn2_m,
    const float* __restrict__ bn2_v,  float* __restrict__ ws)
{
    const int tid = threadIdx.x;
    const int blk = blockIdx.x;
    unsigned short* Wtb = (unsigned short*)(ws + WS_WTB);
    unsigned short* Wob = (unsigned short*)(ws + WS_WOB);
    unsigned short* W1b = (unsigned short*)(ws + WS_W1B);

    if (blk < 800) {
        __shared__ float row[1536];
        const int oc = (blk < 768) ? blk : blk - 768;
        const float* src = (blk < 768) ? (dcn_w + (long)oc * 1536)
                                       : (off_w + (long)oc * 1536);
        for (int i = tid; i < 1536; i += 256) row[i] = src[i];
        float sc = 1.f;
        if (blk < 768) sc = bn2_g[oc] * rsqrtf(bn2_v[oc] + EPS);
        __syncthreads();
        if (tid < 192) {
            int k0 = tid * 8;
            ushort8v o;
#pragma unroll
            for (int t = 0; t < 8; t++) {
                int k = k0 + t;
                int kk = k / 96, c = k % 96;      // k = kk*96 + c
                ((unsigned short*)&o)[t] = f2bf(row[c * 16 + kk] * sc);
            }
            unsigned short* dst = (blk < 768) ? (Wtb + (long)oc * 1536 + k0)
                                              : (Wob + (long)oc * 1536 + k0);
            *(ushort8v*)dst = o;
        }
    } else {
        for (int i = tid; i < 6144; i += 256) {
            int ks = i / 3072, rr = i % 3072;
            int oc = rr >> 5, kl = rr & 31;
            int k = ks * 32 + kl;
            W1b[i] = f2bf(k < 48 ? stem_w[oc * 48 + k] : 0.f);
        }
        if (tid < 96) {
            float s = bn1_g[tid] * rsqrtf(bn1_v[tid] + EPS);
            ws[WS_S1 + tid] = s;
            ws[WS_T1 + tid] = stem_b[tid] * s + bn1_b[tid] - bn1_m[tid] * s;
        }
        for (int i = tid; i < 768; i += 256) {
            float inv2 = bn2_g[i] * rsqrtf(bn2_v[i] + EPS);
            ws[WS_T2 + i] = dcn_b[i] * inv2 + bn2_b[i] - bn2_m[i] * inv2;
        }
    }
}

// ---------------------------------------------------------------------------
// K1: stem conv as bf16 MFMA GEMM, coalesced staging + LDS-repacked stores.
// ---------------------------------------------------------------------------
__global__ __launch_bounds__(256) void k1_stem_mfma(
    const float* __restrict__ x, const unsigned short* __restrict__ W1b,
    const float* __restrict__ s1, const float* __restrict__ t1,
    unsigned short* __restrict__ h1)
{
    const int tid  = threadIdx.x;
    const int wave = tid >> 6, lane = tid & 63;
    const int m = lane & 15, quad = lane >> 4;
    const int p0 = blockIdx.x * 128;

    __shared__ unsigned short sm[14336];   // 28672 B
    unsigned short* sA = sm;               // [2][128][32]
    unsigned short* sB = sm + 8192;        // [2][96][32]

#pragma unroll
    for (int i = 0; i < 3; i++) {
        int inst = wave * 3 + i;
        const unsigned short* g = W1b + inst * 512 + lane * 8;
        __builtin_amdgcn_global_load_lds(
            (const __attribute__((address_space(1))) void*)g,
            (__attribute__((address_space(3))) void*)(sB + inst * 512), 16, 0, 0);
    }
    {
        int r = tid >> 1, off = 16 + (tid & 1) * 8;
        *(ushort8v*)&sA[4096 + r * 32 + off] = (ushort8v)0;
    }
#pragma unroll
    for (int i = 0; i < 6; i++) {
        int unit = i * 256 + tid;
        int r = unit & 127, s = unit >> 7;
        int ci = s >> 2, kh = s & 3;
        int p = p0 + r;
        int b = p / 3136, rem = p % 3136;
        int oy = rem / 56, ox = rem % 56;
        float4 v = *(const float4*)&x[((long)((b * 3 + ci) * 224 + oy * 4 + kh)) * 224 + ox * 4];
        ushort4v hv;
        hv.x = f2bf(v.x); hv.y = f2bf(v.y); hv.z = f2bf(v.z); hv.w = f2bf(v.w);
        int k0i = ci * 16 + kh * 4;
        *(ushort4v*)&sA[(k0i >> 5) * 4096 + r * 32 + (k0i & 31)] = hv;
    }
    __syncthreads();

    bf16x8 bfv[6][2], af[2][2];
#pragma unroll
    for (int j = 0; j < 6; j++)
#pragma unroll
        for (int ks = 0; ks < 2; ks++)
            bfv[j][ks] = *(const bf16x8*)&sB[ks * 3072 + (j * 16 + m) * 32 + quad * 8];
#pragma unroll
    for (int rt = 0; rt < 2; rt++)
#pragma unroll
        for (int ks = 0; ks < 2; ks++)
            af[rt][ks] = *(const bf16x8*)&sA[ks * 4096 + (wave * 32 + rt * 16 + m) * 32 + quad * 8];

    floatx4 acc[2][6];
#pragma unroll
    for (int rt = 0; rt < 2; rt++)
#pragma unroll
        for (int j = 0; j < 6; j++) {
            floatx4 a = (floatx4)0.f;
            a = __builtin_amdgcn_mfma_f32_16x16x32_bf16(af[rt][0], bfv[j][0], a, 0, 0, 0);
            a = __builtin_amdgcn_mfma_f32_16x16x32_bf16(af[rt][1], bfv[j][1], a, 0, 0, 0);
            acc[rt][j] = a;
        }

    __syncthreads();
#pragma unroll
    for (int j = 0; j < 6; j++) {
        int c = j * 16 + m;
        float sc = s1[c], bi = t1[c];
#pragma unroll
        for (int rt = 0; rt < 2; rt++)
#pragma unroll
            for (int r = 0; r < 4; r++) {
                int row = wave * 32 + rt * 16 + quad * 4 + r;
                float v = acc[rt][j][r] * sc + bi;
                v = v >= 0.f ? v : SLOPE * v;
                sm[row * 96 + c] = f2bf(v);
            }
    }
    __syncthreads();
#pragma unroll
    for (int i = 0; i < 6; i++) {
        int idx = (i * 256 + tid) * 8;
        *(ushort8v*)&h1[(long)p0 * 96 + idx] = *(const ushort8v*)&sm[idx];
    }
}

// ---------------------------------------------------------------------------
// K2: offset conv, K-split x4 across blocks + dbuf prefetch + atomic reduce.
// Block bx: nt = bx%98, ks = bx/98 handles k in [ks*384, ks*384+384).
// off must be memset to 0 beforehand; ks==0 partial adds off_b.
// ---------------------------------------------------------------------------
__global__ __launch_bounds__(256) void k2_mfma(
    const unsigned short* __restrict__ h1,   // bf16 NHWC
    const unsigned short* __restrict__ Wob,  // [32][1536] bf16
    const float* __restrict__ off_b, float* __restrict__ off)
{
    const int tid  = threadIdx.x;
    const int wave = tid >> 6, lane = tid & 63;
    const int m = lane & 15, quad = lane >> 4;
    const int nt = blockIdx.x % 98, ks = blockIdx.x / 98;
    const int n0 = nt * 128;

    __shared__ unsigned short sA[2][4096];   // [buf][128*32]
    __shared__ unsigned short sB[2][1024];   // [buf][32*32]

    const int skoff = (lane & 3) * 8;
    int n_a = n0 + wave * 32 + (lane >> 2);
    int n_b = n_a + 16;
    int ba = n_a / 196, pa = n_a % 196;
    int bb = n_b / 196, pb = n_b % 196;
    long pixa = ((long)(ba * 56 + (pa / 14) * 4) * 56 + (pa % 14) * 4);
    long pixb = ((long)(bb * 56 + (pb / 14) * 4) * 56 + (pb % 14) * 4);

    const unsigned short* gB = Wob + (long)(wave * 16 + (lane >> 2)) * 1536 + ks * 384 + skoff;
    const int lofA0 = (wave * 32) * 32;
    const int lofA1 = (wave * 32 + 16) * 32;
    const int lofB  = (wave * 16) * 32;

    auto issue = [&](int buf, int kt) {
        int khw = ks * 4 + kt / 3;
        int c0  = (kt % 3) * 32;
        int kh  = khw >> 2, kw = khw & 3;
        long eoff = (long)(kh * 56 + kw) * 96 + c0 + skoff;
        __builtin_amdgcn_global_load_lds(
            (const __attribute__((address_space(1))) void*)(h1 + pixa * 96 + eoff),
            (__attribute__((address_space(3))) void*)&sA[buf][lofA0], 16, 0, 0);
        __builtin_amdgcn_global_load_lds(
            (const __attribute__((address_space(1))) void*)(h1 + pixb * 96 + eoff),
            (__attribute__((address_space(3))) void*)&sA[buf][lofA1], 16, 0, 0);
        if (wave < 2)
            __builtin_amdgcn_global_load_lds(
                (const __attribute__((address_space(1))) void*)(gB + kt * 32),
                (__attribute__((address_space(3))) void*)&sB[buf][lofB], 16, 0, 0);
    };

    floatx4 acc[2][2];
#pragma unroll
    for (int i = 0; i < 2; i++)
#pragma unroll
        for (int j = 0; j < 2; j++) acc[i][j] = (floatx4)0.f;

    issue(0, 0);
    for (int kt = 0; kt < 12; ++kt) {
        __syncthreads();                       // drains tile kt's loads
        if (kt < 11) issue((kt + 1) & 1, kt + 1);
        const unsigned short* bufA = sA[kt & 1];
        const unsigned short* bufB = sB[kt & 1];
        bf16x8 af[2], bfr[2];
#pragma unroll
        for (int i = 0; i < 2; i++)
            af[i] = *(const bf16x8*)&bufA[(wave * 32 + i * 16 + m) * 32 + quad * 8];
#pragma unroll
        for (int j = 0; j < 2; j++)
            bfr[j] = *(const bf16x8*)&bufB[(j * 16 + m) * 32 + quad * 8];
#pragma unroll
        for (int i = 0; i < 2; i++)
#pragma unroll
            for (int j = 0; j < 2; j++)
                acc[i][j] = __builtin_amdgcn_mfma_f32_16x16x32_bf16(
                    af[i], bfr[j], acc[i][j], 0, 0, 0);
    }

    float tb[2];
#pragma unroll
    for (int j = 0; j < 2; j++) tb[j] = (ks == 0) ? off_b[j * 16 + m] : 0.f;
#pragma unroll
    for (int i = 0; i < 2; i++)
#pragma unroll
        for (int r = 0; r < 4; r++) {
            long n = n0 + wave * 32 + i * 16 + quad * 4 + r;
#pragma unroll
            for (int j = 0; j < 2; j++)
                atomicAdd(&off[n * 32 + j * 16 + m], acc[i][j][r] + tb[j]);
        }
}

// ---------------------------------------------------------------------------
// K3: bilinear sampling from bf16 h1 -> S bf16 [n][k], k = kk*96 + c.
// ---------------------------------------------------------------------------
__global__ __launch_bounds__(384) void k3_sample(
    const unsigned short* __restrict__ h1, const float* __restrict__ off,
    unsigned short* __restrict__ S)
{
    const int p = blockIdx.x;     // 0..195
    const int b = blockIdx.y;     // 0..63
    const int y = p / 14, xo = p % 14;
    const int tid = threadIdx.x;
    const int c4 = tid % 24, kk = tid / 24;
    const int kh = kk >> 2, kw = kk & 3;

    const float* ob = off + ((long)(b * 196 + p)) * 32;
    float dy = ob[kk * 2];
    float dx = ob[kk * 2 + 1];

    float py = (float)(y * 4 + kh) + dy;
    float px = (float)(xo * 4 + kw) + dx;
    float y0f = floorf(py), x0f = floorf(px);
    float wy = py - y0f, wx = px - x0f;
    int y0 = (int)y0f, x0 = (int)x0f;
    int y1 = y0 + 1,  x1 = x0 + 1;

    float my0 = (y0 >= 0 && y0 < 56) ? 1.f : 0.f;
    float my1 = (y1 >= 0 && y1 < 56) ? 1.f : 0.f;
    float mx0 = (x0 >= 0 && x0 < 56) ? 1.f : 0.f;
    float mx1 = (x1 >= 0 && x1 < 56) ? 1.f : 0.f;
    int y0c = min(max(y0, 0), 55), y1c = min(max(y1, 0), 55);
    int x0c = min(max(x0, 0), 55), x1c = min(max(x1, 0), 55);

    const unsigned short* hb = h1 + (long)b * 56 * 56 * 96 + c4 * 4;
    ushort4v v00 = *(const ushort4v*)&hb[(y0c * 56 + x0c) * 96];
    ushort4v v01 = *(const ushort4v*)&hb[(y0c * 56 + x1c) * 96];
    ushort4v v10 = *(const ushort4v*)&hb[(y1c * 56 + x0c) * 96];
    ushort4v v11 = *(const ushort4v*)&hb[(y1c * 56 + x1c) * 96];

    float w00 = my0 * mx0 * (1.f - wy) * (1.f - wx);
    float w01 = my0 * mx1 * (1.f - wy) * wx;
    float w10 = my1 * mx0 * wy * (1.f - wx);
    float w11 = my1 * mx1 * wy * wx;

    ushort4v rr;
#pragma unroll
    for (int c = 0; c < 4; c++) {
        float v = bf2f(((unsigned short*)&v00)[c]) * w00
                + bf2f(((unsigned short*)&v01)[c]) * w01
                + bf2f(((unsigned short*)&v10)[c]) * w10
                + bf2f(((unsigned short*)&v11)[c]) * w11;
        ((unsigned short*)&rr)[c] = f2bf(v);
    }

    long n = (long)b * 196 + p;
    *(ushort4v*)&S[n * 1536 + kk * 96 + c4 * 4] = rr;
}

// ---------------------------------------------------------------------------
// K4: bf16 MFMA GEMM  C[n][oc] = S[n][k] * Wtb[oc][k]^T  (N=12544,M=768,K=1536)
// 128n x 128oc tile, 4 waves each computing a 64x64 sub-tile (wr=wave>>1,
// wc=wave&1). LDS-READ-PORT ANALYSIS (rounds 0/1 both 66us with identical
// 1.354M total ds_read_b128 despite 2x different MFMA-per-barrier): k4 is
// bound by ds_read_b128 throughput (~12cyc each = 40% of kernel cycles).
// 64x64 wave tile -> (4+4) reads per 16 MFMA = 0.5 reads/MFMA (was 0.75),
// total reads 1.354M -> 903k. BK=64, 24 steps, proven round-1 dbuf +
// __syncthreads (round-2 counted-vmcnt regressed: occupancy + L2 loss).
// LDS 64KB (2 bufs x (16KB A + 16KB B)) -> 2 blocks/CU (= measured residency).
// Rows are 128B -> XOR-swizzle slot^=(row&7) keeps ds_read conflict-free
// (verified round 1: SQ_LDS_BANK_CONFLICT == 0); gload_lds dest linear,
// SOURCE k-offset pre-swizzled per-lane, reads apply the same XOR.
// Grid 588 (98 n-tiles x 6 oc-tiles); 588%8!=0 -> bijective XCD swizzle
// (m204): q=73,r=4.
// ---------------------------------------------------------------------------
__global__ __launch_bounds__(256) void k4_gemm_mfma(
    const unsigned short* __restrict__ S,    // [12544][1536] bf16
    const unsigned short* __restrict__ Wtb,  // [768][1536]  bf16 (B^T, scaled)
    const float* __restrict__ t2, float* __restrict__ out)
{
    const int tid  = threadIdx.x;
    const int wave = tid >> 6, lane = tid & 63;

    // bijective XCD swizzle for nwg=588: q=73, r=4
    int lid = blockIdx.x;
    int xcd = lid & 7, pos = lid >> 3;
    int work = ((xcd < 4) ? xcd * 74 : 296 + (xcd - 4) * 73) + pos;
    const int n0  = (work / 6) * 128;
    const int oc0 = (work % 6) * 128;

    const int wr = wave >> 1, wc = wave & 1;
    const int m = lane & 15, quad = lane >> 4;

    __shared__ unsigned short sA[2][8192];   // [buf][128 rows * 64 k] 32KB
    __shared__ unsigned short sB[2][8192];   // [buf][128 rows * 64 k] 32KB

    // staging geometry: one global_load_lds = 64 lanes x 16B = 8 rows of 128B.
    // lane -> row lr = lane>>3, 16B slot ls = lane&7.
    // LDS slot s of row r holds logical k-chunk s ^ (r&7); source fetches
    // chunk ls^lr (r&7 == lr since all row bases are multiples of 8).
    const int lr = lane >> 3;
    const int ls = lane & 7;
    const int swzk = ((ls ^ lr) * 8);        // element offset within 64-k row

    const unsigned short* gA[4];
    const unsigned short* gB[4];
#pragma unroll
    for (int t = 0; t < 4; t++) {
        gA[t] = S   + (long)(n0  + wave * 32 + t * 8 + lr) * 1536 + swzk;
        gB[t] = Wtb + (long)(oc0 + wave * 32 + t * 8 + lr) * 1536 + swzk;
    }

    auto issue = [&](int buf) {
#pragma unroll
        for (int t = 0; t < 4; t++) {
            __builtin_amdgcn_global_load_lds(
                (const __attribute__((address_space(1))) void*)gA[t],
                (__attribute__((address_space(3))) void*)&sA[buf][(wave * 32 + t * 8) * 64],
                16, 0, 0);
            gA[t] += 64;
            __builtin_amdgcn_global_load_lds(
                (const __attribute__((address_space(1))) void*)gB[t],
                (__attribute__((address_space(3))) void*)&sB[buf][(wave * 32 + t * 8) * 64],
                16, 0, 0);
            gB[t] += 64;
        }
    };

    floatx4 acc[4][4];
#pragma unroll
    for (int i = 0; i < 4; i++)
#pragma unroll
        for (int j = 0; j < 4; j++) acc[i][j] = (floatx4)0.f;

    issue(0);
    for (int kt = 0; kt < 24; ++kt) {
        __syncthreads();                     // drains tile kt's loads (vmcnt)
        if (kt < 23) issue((kt + 1) & 1);    // prefetch flies during compute
        const unsigned short* bufA = sA[kt & 1];
        const unsigned short* bufB = sB[kt & 1];
        // read swizzle: logical 16B-chunk (ks*4+quad) of row r lives at
        // slot (ks*4+quad)^(r&7); r&7 == m&7 for all fragment rows.
        bf16x8 af[4][2], bfr[4][2];
#pragma unroll
        for (int i = 0; i < 4; i++)
#pragma unroll
            for (int ks = 0; ks < 2; ks++)
                af[i][ks] = *(const bf16x8*)&bufA[(wr * 64 + i * 16 + m) * 64
                                                 + (((ks * 4 + quad) ^ (m & 7)) * 8)];
#pragma unroll
        for (int j = 0; j < 4; j++)
#pragma unroll
            for (int ks = 0; ks < 2; ks++)
                bfr[j][ks] = *(const bf16x8*)&bufB[(wc * 64 + j * 16 + m) * 64
                                                  + (((ks * 4 + quad) ^ (m & 7)) * 8)];
#pragma unroll
        for (int i = 0; i < 4; i++)
#pragma unroll
            for (int j = 0; j < 4; j++) {
                acc[i][j] = __builtin_amdgcn_mfma_f32_16x16x32_bf16(
                    af[i][0], bfr[j][0], acc[i][j], 0, 0, 0);
                acc[i][j] = __builtin_amdgcn_mfma_f32_16x16x32_bf16(
                    af[i][1], bfr[j][1], acc[i][j], 0, 0, 0);
            }
    }

    float tb[4];
#pragma unroll
    for (int j = 0; j < 4; j++) tb[j] = t2[oc0 + wc * 64 + j * 16 + m];
#pragma unroll
    for (int i = 0; i < 4; i++) {
#pragma unroll
        for (int r = 0; r < 4; r++) {
            long n = n0 + wr * 64 + i * 16 + quad * 4 + r;
            float* orow = out + n * 768 + oc0 + wc * 64 + m;
#pragma unroll
            for (int j = 0; j < 4; j++) {
                float v = acc[i][j][r] + tb[j];
                orow[j * 16] = v >= 0.f ? v : SLOPE * v;
            }
        }
    }
}

// ---------------------------------------------------------------------------
extern "C" void kernel_launch(void* const* d_in, const int* in_sizes, int n_in,
                              void* d_out, int out_size, void* d_ws, size_t ws_size,
                              hipStream_t stream)
{
    const float* x      = (const float*)d_in[0];
    const float* stem_w = (const float*)d_in[1];
    const float* stem_b = (const float*)d_in[2];
    const float* bn1_g  = (const float*)d_in[3];
    const float* bn1_b  = (const float*)d_in[4];
    const float* bn1_m  = (const float*)d_in[5];
    const float* bn1_v  = (const float*)d_in[6];
    const float* off_w  = (const float*)d_in[7];
    const float* off_b  = (const float*)d_in[8];
    const float* dcn_w  = (const float*)d_in[9];
    const float* dcn_b  = (const float*)d_in[10];
    const float* bn2_g  = (const float*)d_in[11];
    const float* bn2_b  = (const float*)d_in[12];
    const float* bn2_m  = (const float*)d_in[13];
    const float* bn2_v  = (const float*)d_in[14];

    float* ws  = (float*)d_ws;        // needs 81.2 MB
    float* out = (float*)d_out;

    unsigned short* h1  = (unsigned short*)(ws + WS_H1B);
    float* off = ws + WS_OFF;
    float* s1  = ws + WS_S1;
    float* t1  = ws + WS_T1;
    float* t2  = ws + WS_T2;
    unsigned short* Sb  = (unsigned short*)(ws + WS_SB);
    unsigned short* Wtb = (unsigned short*)(ws + WS_WTB);
    unsigned short* Wob = (unsigned short*)(ws + WS_WOB);
    unsigned short* W1b = (unsigned short*)(ws + WS_W1B);

    k0_prep<<<801, 256, 0, stream>>>(stem_w, stem_b, bn1_g, bn1_b, bn1_m, bn1_v,
                                     off_w, dcn_w, dcn_b, bn2_g, bn2_b, bn2_m,
                                     bn2_v, ws);
    // zero the atomic-accumulated offset buffer (re-poisoned 0xAA each launch)
    hipMemsetAsync(off, 0, 401408 * sizeof(float), stream);
    k1_stem_mfma<<<1568, 256, 0, stream>>>(x, W1b, s1, t1, h1);
    k2_mfma<<<392, 256, 0, stream>>>(h1, Wob, off_b, off);
    k3_sample<<<dim3(196, 64), 384, 0, stream>>>(h1, off, Sb);
    k4_gemm_mfma<<<588, 256, 0, stream>>>(Sb, Wtb, t2, out);
}

// Round 4
// 213.178 us; speedup vs baseline: 1.0895x; 1.0190x over previous
//
#include <hip/hip_runtime.h>

#define EPS   1e-5f
#define SLOPE 0.01f

// ---------------------------------------------------------------------------
// Workspace layout (float offsets). Total 20,287,424 floats = 81.1 MB.
// ---------------------------------------------------------------------------
#define WS_H1B  0L            // h1  bf16 NHWC (64,56,56,96)   (9633792 f)
#define WS_OFF  9633792L      // off f32 [n=12544][32]            401408
#define WS_S1   10035200L     // bn1 scale f32 [96]
#define WS_T1   10035296L     // bn1 bias  f32 [96]
#define WS_T2   10035392L     // fused dcn_b+bn2 bias f32 [768]
#define WS_SB   10036160L     // S   bf16 [n=12544][k=1536]    (9633792 f)
#define WS_WTB  19669952L     // Wtb bf16 [oc=768][k=1536]      (589824 f)
#define WS_WOB  20259776L     // Wob bf16 [oc=32][k=1536]        (24576 f)
#define WS_W1B  20284352L     // W1b bf16 [ks=2][oc=96][kl=32]    (3072 f)

__device__ __forceinline__ unsigned short f2bf(float f) {
    unsigned int u = __builtin_bit_cast(unsigned int, f);
    u += 0x7fffu + ((u >> 16) & 1u);
    return (unsigned short)(u >> 16);
}
__device__ __forceinline__ float bf2f(unsigned short u) {
    unsigned int t = ((unsigned int)u) << 16;
    return __builtin_bit_cast(float, t);
}

typedef __attribute__((ext_vector_type(4))) unsigned short ushort4v;
typedef __attribute__((ext_vector_type(8))) unsigned short ushort8v;
typedef __attribute__((ext_vector_type(8))) short bf16x8;
typedef __attribute__((ext_vector_type(4))) float floatx4;

__device__ __forceinline__ floatx4 mfma16(bf16x8 a, bf16x8 b, floatx4 c) {
    return __builtin_amdgcn_mfma_f32_16x16x32_bf16(a, b, c, 0, 0, 0);
}

// ---------------------------------------------------------------------------
// K0: weight prep, transpose-via-LDS for coalescing.
// ---------------------------------------------------------------------------
__global__ __launch_bounds__(256) void k0_prep(
    const float* __restrict__ stem_w, const float* __restrict__ stem_b,
    const float* __restrict__ bn1_g,  const float* __restrict__ bn1_b,
    const float* __restrict__ bn1_m,  const float* __restrict__ bn1_v,
    const float* __restrict__ off_w,  const float* __restrict__ dcn_w,
    const float* __restrict__ dcn_b,  const float* __restrict__ bn2_g,
    const float* __restrict__ bn2_b,  const float* __restrict__ bn2_m,
    const float* __restrict__ bn2_v,  float* __restrict__ ws)
{
    const int tid = threadIdx.x;
    const int blk = blockIdx.x;
    unsigned short* Wtb = (unsigned short*)(ws + WS_WTB);
    unsigned short* Wob = (unsigned short*)(ws + WS_WOB);
    unsigned short* W1b = (unsigned short*)(ws + WS_W1B);

    if (blk < 800) {
        __shared__ float row[1536];
        const int oc = (blk < 768) ? blk : blk - 768;
        const float* src = (blk < 768) ? (dcn_w + (long)oc * 1536)
                                       : (off_w + (long)oc * 1536);
        for (int i = tid; i < 1536; i += 256) row[i] = src[i];
        float sc = 1.f;
        if (blk < 768) sc = bn2_g[oc] * rsqrtf(bn2_v[oc] + EPS);
        __syncthreads();
        if (tid < 192) {
            int k0 = tid * 8;
            ushort8v o;
#pragma unroll
            for (int t = 0; t < 8; t++) {
                int k = k0 + t;
                int kk = k / 96, c = k % 96;      // k = kk*96 + c
                ((unsigned short*)&o)[t] = f2bf(row[c * 16 + kk] * sc);
            }
            unsigned short* dst = (blk < 768) ? (Wtb + (long)oc * 1536 + k0)
                                              : (Wob + (long)oc * 1536 + k0);
            *(ushort8v*)dst = o;
        }
    } else {
        for (int i = tid; i < 6144; i += 256) {
            int ks = i / 3072, rr = i % 3072;
            int oc = rr >> 5, kl = rr & 31;
            int k = ks * 32 + kl;
            W1b[i] = f2bf(k < 48 ? stem_w[oc * 48 + k] : 0.f);
        }
        if (tid < 96) {
            float s = bn1_g[tid] * rsqrtf(bn1_v[tid] + EPS);
            ws[WS_S1 + tid] = s;
            ws[WS_T1 + tid] = stem_b[tid] * s + bn1_b[tid] - bn1_m[tid] * s;
        }
        for (int i = tid; i < 768; i += 256) {
            float inv2 = bn2_g[i] * rsqrtf(bn2_v[i] + EPS);
            ws[WS_T2 + i] = dcn_b[i] * inv2 + bn2_b[i] - bn2_m[i] * inv2;
        }
    }
}

// ---------------------------------------------------------------------------
// K1: stem conv as bf16 MFMA GEMM, coalesced staging + LDS-repacked stores.
// ---------------------------------------------------------------------------
__global__ __launch_bounds__(256) void k1_stem_mfma(
    const float* __restrict__ x, const unsigned short* __restrict__ W1b,
    const float* __restrict__ s1, const float* __restrict__ t1,
    unsigned short* __restrict__ h1)
{
    const int tid  = threadIdx.x;
    const int wave = tid >> 6, lane = tid & 63;
    const int m = lane & 15, quad = lane >> 4;
    const int p0 = blockIdx.x * 128;

    __shared__ unsigned short sm[14336];   // 28672 B
    unsigned short* sA = sm;               // [2][128][32]
    unsigned short* sB = sm + 8192;        // [2][96][32]

#pragma unroll
    for (int i = 0; i < 3; i++) {
        int inst = wave * 3 + i;
        const unsigned short* g = W1b + inst * 512 + lane * 8;
        __builtin_amdgcn_global_load_lds(
            (const __attribute__((address_space(1))) void*)g,
            (__attribute__((address_space(3))) void*)(sB + inst * 512), 16, 0, 0);
    }
    {
        int r = tid >> 1, off = 16 + (tid & 1) * 8;
        *(ushort8v*)&sA[4096 + r * 32 + off] = (ushort8v)0;
    }
#pragma unroll
    for (int i = 0; i < 6; i++) {
        int unit = i * 256 + tid;
        int r = unit & 127, s = unit >> 7;
        int ci = s >> 2, kh = s & 3;
        int p = p0 + r;
        int b = p / 3136, rem = p % 3136;
        int oy = rem / 56, ox = rem % 56;
        float4 v = *(const float4*)&x[((long)((b * 3 + ci) * 224 + oy * 4 + kh)) * 224 + ox * 4];
        ushort4v hv;
        hv.x = f2bf(v.x); hv.y = f2bf(v.y); hv.z = f2bf(v.z); hv.w = f2bf(v.w);
        int k0i = ci * 16 + kh * 4;
        *(ushort4v*)&sA[(k0i >> 5) * 4096 + r * 32 + (k0i & 31)] = hv;
    }
    __syncthreads();

    bf16x8 bfv[6][2], af[2][2];
#pragma unroll
    for (int j = 0; j < 6; j++)
#pragma unroll
        for (int ks = 0; ks < 2; ks++)
            bfv[j][ks] = *(const bf16x8*)&sB[ks * 3072 + (j * 16 + m) * 32 + quad * 8];
#pragma unroll
    for (int rt = 0; rt < 2; rt++)
#pragma unroll
        for (int ks = 0; ks < 2; ks++)
            af[rt][ks] = *(const bf16x8*)&sA[ks * 4096 + (wave * 32 + rt * 16 + m) * 32 + quad * 8];

    floatx4 acc[2][6];
#pragma unroll
    for (int rt = 0; rt < 2; rt++)
#pragma unroll
        for (int j = 0; j < 6; j++) {
            floatx4 a = (floatx4)0.f;
            a = __builtin_amdgcn_mfma_f32_16x16x32_bf16(af[rt][0], bfv[j][0], a, 0, 0, 0);
            a = __builtin_amdgcn_mfma_f32_16x16x32_bf16(af[rt][1], bfv[j][1], a, 0, 0, 0);
            acc[rt][j] = a;
        }

    __syncthreads();
#pragma unroll
    for (int j = 0; j < 6; j++) {
        int c = j * 16 + m;
        float sc = s1[c], bi = t1[c];
#pragma unroll
        for (int rt = 0; rt < 2; rt++)
#pragma unroll
            for (int r = 0; r < 4; r++) {
                int row = wave * 32 + rt * 16 + quad * 4 + r;
                float v = acc[rt][j][r] * sc + bi;
                v = v >= 0.f ? v : SLOPE * v;
                sm[row * 96 + c] = f2bf(v);
            }
    }
    __syncthreads();
#pragma unroll
    for (int i = 0; i < 6; i++) {
        int idx = (i * 256 + tid) * 8;
        *(ushort8v*)&h1[(long)p0 * 96 + idx] = *(const ushort8v*)&sm[idx];
    }
}

// ---------------------------------------------------------------------------
// K2: offset conv, K-split x4 across blocks + dbuf prefetch + atomic reduce.
// ---------------------------------------------------------------------------
__global__ __launch_bounds__(256) void k2_mfma(
    const unsigned short* __restrict__ h1,   // bf16 NHWC
    const unsigned short* __restrict__ Wob,  // [32][1536] bf16
    const float* __restrict__ off_b, float* __restrict__ off)
{
    const int tid  = threadIdx.x;
    const int wave = tid >> 6, lane = tid & 63;
    const int m = lane & 15, quad = lane >> 4;
    const int nt = blockIdx.x % 98, ks = blockIdx.x / 98;
    const int n0 = nt * 128;

    __shared__ unsigned short sA[2][4096];   // [buf][128*32]
    __shared__ unsigned short sB[2][1024];   // [buf][32*32]

    const int skoff = (lane & 3) * 8;
    int n_a = n0 + wave * 32 + (lane >> 2);
    int n_b = n_a + 16;
    int ba = n_a / 196, pa = n_a % 196;
    int bb = n_b / 196, pb = n_b % 196;
    long pixa = ((long)(ba * 56 + (pa / 14) * 4) * 56 + (pa % 14) * 4);
    long pixb = ((long)(bb * 56 + (pb / 14) * 4) * 56 + (pb % 14) * 4);

    const unsigned short* gB = Wob + (long)(wave * 16 + (lane >> 2)) * 1536 + ks * 384 + skoff;
    const int lofA0 = (wave * 32) * 32;
    const int lofA1 = (wave * 32 + 16) * 32;
    const int lofB  = (wave * 16) * 32;

    auto issue = [&](int buf, int kt) {
        int khw = ks * 4 + kt / 3;
        int c0  = (kt % 3) * 32;
        int kh  = khw >> 2, kw = khw & 3;
        long eoff = (long)(kh * 56 + kw) * 96 + c0 + skoff;
        __builtin_amdgcn_global_load_lds(
            (const __attribute__((address_space(1))) void*)(h1 + pixa * 96 + eoff),
            (__attribute__((address_space(3))) void*)&sA[buf][lofA0], 16, 0, 0);
        __builtin_amdgcn_global_load_lds(
            (const __attribute__((address_space(1))) void*)(h1 + pixb * 96 + eoff),
            (__attribute__((address_space(3))) void*)&sA[buf][lofA1], 16, 0, 0);
        if (wave < 2)
            __builtin_amdgcn_global_load_lds(
                (const __attribute__((address_space(1))) void*)(gB + kt * 32),
                (__attribute__((address_space(3))) void*)&sB[buf][lofB], 16, 0, 0);
    };

    floatx4 acc[2][2];
#pragma unroll
    for (int i = 0; i < 2; i++)
#pragma unroll
        for (int j = 0; j < 2; j++) acc[i][j] = (floatx4)0.f;

    issue(0, 0);
    for (int kt = 0; kt < 12; ++kt) {
        __syncthreads();                       // drains tile kt's loads
        if (kt < 11) issue((kt + 1) & 1, kt + 1);
        const unsigned short* bufA = sA[kt & 1];
        const unsigned short* bufB = sB[kt & 1];
        bf16x8 af[2], bfr[2];
#pragma unroll
        for (int i = 0; i < 2; i++)
            af[i] = *(const bf16x8*)&bufA[(wave * 32 + i * 16 + m) * 32 + quad * 8];
#pragma unroll
        for (int j = 0; j < 2; j++)
            bfr[j] = *(const bf16x8*)&bufB[(j * 16 + m) * 32 + quad * 8];
#pragma unroll
        for (int i = 0; i < 2; i++)
#pragma unroll
            for (int j = 0; j < 2; j++)
                acc[i][j] = __builtin_amdgcn_mfma_f32_16x16x32_bf16(
                    af[i], bfr[j], acc[i][j], 0, 0, 0);
    }

    float tb[2];
#pragma unroll
    for (int j = 0; j < 2; j++) tb[j] = (ks == 0) ? off_b[j * 16 + m] : 0.f;
#pragma unroll
    for (int i = 0; i < 2; i++)
#pragma unroll
        for (int r = 0; r < 4; r++) {
            long n = n0 + wave * 32 + i * 16 + quad * 4 + r;
#pragma unroll
            for (int j = 0; j < 2; j++)
                atomicAdd(&off[n * 32 + j * 16 + m], acc[i][j][r] + tb[j]);
        }
}

// ---------------------------------------------------------------------------
// K3: bilinear sampling from bf16 h1 -> S bf16 [n][k], k = kk*96 + c.
// ---------------------------------------------------------------------------
__global__ __launch_bounds__(384) void k3_sample(
    const unsigned short* __restrict__ h1, const float* __restrict__ off,
    unsigned short* __restrict__ S)
{
    const int p = blockIdx.x;     // 0..195
    const int b = blockIdx.y;     // 0..63
    const int y = p / 14, xo = p % 14;
    const int tid = threadIdx.x;
    const int c4 = tid % 24, kk = tid / 24;
    const int kh = kk >> 2, kw = kk & 3;

    const float* ob = off + ((long)(b * 196 + p)) * 32;
    float dy = ob[kk * 2];
    float dx = ob[kk * 2 + 1];

    float py = (float)(y * 4 + kh) + dy;
    float px = (float)(xo * 4 + kw) + dx;
    float y0f = floorf(py), x0f = floorf(px);
    float wy = py - y0f, wx = px - x0f;
    int y0 = (int)y0f, x0 = (int)x0f;
    int y1 = y0 + 1,  x1 = x0 + 1;

    float my0 = (y0 >= 0 && y0 < 56) ? 1.f : 0.f;
    float my1 = (y1 >= 0 && y1 < 56) ? 1.f : 0.f;
    float mx0 = (x0 >= 0 && x0 < 56) ? 1.f : 0.f;
    float mx1 = (x1 >= 0 && x1 < 56) ? 1.f : 0.f;
    int y0c = min(max(y0, 0), 55), y1c = min(max(y1, 0), 55);
    int x0c = min(max(x0, 0), 55), x1c = min(max(x1, 0), 55);

    const unsigned short* hb = h1 + (long)b * 56 * 56 * 96 + c4 * 4;
    ushort4v v00 = *(const ushort4v*)&hb[(y0c * 56 + x0c) * 96];
    ushort4v v01 = *(const ushort4v*)&hb[(y0c * 56 + x1c) * 96];
    ushort4v v10 = *(const ushort4v*)&hb[(y1c * 56 + x0c) * 96];
    ushort4v v11 = *(const ushort4v*)&hb[(y1c * 56 + x1c) * 96];

    float w00 = my0 * mx0 * (1.f - wy) * (1.f - wx);
    float w01 = my0 * mx1 * (1.f - wy) * wx;
    float w10 = my1 * mx0 * wy * (1.f - wx);
    float w11 = my1 * mx1 * wy * wx;

    ushort4v rr;
#pragma unroll
    for (int c = 0; c < 4; c++) {
        float v = bf2f(((unsigned short*)&v00)[c]) * w00
                + bf2f(((unsigned short*)&v01)[c]) * w01
                + bf2f(((unsigned short*)&v10)[c]) * w10
                + bf2f(((unsigned short*)&v11)[c]) * w11;
        ((unsigned short*)&rr)[c] = f2bf(v);
    }

    long n = (long)b * 196 + p;
    *(ushort4v*)&S[n * 1536 + kk * 96 + c4 * 4] = rr;
}

// ---------------------------------------------------------------------------
// K4: bf16 MFMA GEMM  C[n][oc] = S[n][k] * Wtb[oc][k]^T  (N=12544,M=768,K=1536)
// 8-PHASE COUNTED-VMCNT TEMPLATE (T2+T3+T4+T5, m201 geometry):
//   BM=BN=256, BK=64, 512 threads = 8 waves (2x4), per-wave out 128x64,
//   acc[8][4] = 128 AGPRs. Grid = 49 x 3 = 147 blocks -> every block owns a
//   CU for the whole kernel (no serial block generations); wall time =
//   24 K-tiles x per-tile cost.
// Latency analysis (r0-r3): per-K-step drain latency ~2.2-2.9k cyc constant
// across all tile shapes = the 2-phase stall (m233). Fix is structural:
// per K-tile 4 phases, each {ds_read subtile | issue 1 staging chunk ->
// barrier -> setprio(1) 16 MFMA setprio(0) -> barrier}; ONE s_waitcnt
// vmcnt(2) per K-tile (never 0 mid-loop) so tile t+1's 8 loads stay in
// flight across all of tile t's phases (~full-K-tile latency hiding).
// vmcnt ledger (per wave): prologue 8 in flight; +2 per phase; at phase 0
// after issuing chunk0(t+1): 10 outstanding -> vmcnt(2) retires tile t's 8
// (in-order), keeps t+1 chunk0 airborne.
// LDS 128KB (2 bufs x (32KB A + 32KB B)) -> 1 block/CU, 2 waves/SIMD.
// Rows 128B -> XOR-swizzle slot^=(row&7), conflict-free (verified r1/r3:
// SQ_LDS_BANK_CONFLICT == 0); gload_lds dest linear, SOURCE pre-swizzled.
// 147 blocks: XCD grouping (147 = 3x19 + 5x18) keeps the 3 oc-blocks of
// each n-tile on one XCD -> S-slice fetched ~once from HBM.
// ---------------------------------------------------------------------------
__global__ __launch_bounds__(512, 2) void k4_gemm_mfma(
    const unsigned short* __restrict__ S,    // [12544][1536] bf16
    const unsigned short* __restrict__ Wtb,  // [768][1536]  bf16 (B^T, scaled)
    const float* __restrict__ t2, float* __restrict__ out)
{
    const int tid  = threadIdx.x;
    const int wave = tid >> 6, lane = tid & 63;

    // bijective XCD grouping for nwg=147: q=18, r=3
    int b = blockIdx.x;
    int xcd = b & 7, pos = b >> 3;
    int work = ((xcd < 3) ? xcd * 19 : 57 + (xcd - 3) * 18) + pos;
    const int n0  = (work / 3) * 256;
    const int oc0 = (work % 3) * 256;

    const int wr = wave >> 2, wc = wave & 3;     // 2 x 4 wave grid
    const int m = lane & 15, quad = lane >> 4;

    __shared__ unsigned short sA[2][16384];      // [buf][256 rows * 64 k] 64KB
    __shared__ unsigned short sB[2][16384];      // [buf][256 rows * 64 k] 64KB

    // staging: one gload_lds = 64 lanes x 16B = 8 rows of 128B.
    // lane -> row lr = lane>>3, slot ls = lane&7; LDS slot s of row r holds
    // logical k-chunk s^(r&7); source fetches chunk ls^lr.
    const int lr = lane >> 3;
    const int ls = lane & 7;
    const int swzk = ((ls ^ lr) * 8);            // element offset in 64-k row

    // 4 chunks per K-tile: A rows [0,128), A rows [128,256), B [0,128), B [128,256).
    // each chunk = 16 wave-instrs = 2 per wave (rows wave*16+{0,8}).
    const unsigned short* pA0  = S   + (long)(n0  + wave * 16 + lr) * 1536 + swzk;
    const unsigned short* pA0b = pA0 + 8 * 1536;
    const unsigned short* pA1  = pA0 + 128 * 1536;
    const unsigned short* pA1b = pA1 + 8 * 1536;
    const unsigned short* pB0  = Wtb + (long)(oc0 + wave * 16 + lr) * 1536 + swzk;
    const unsigned short* pB0b = pB0 + 8 * 1536;
    const unsigned short* pB1  = pB0 + 128 * 1536;
    const unsigned short* pB1b = pB1 + 8 * 1536;

    const int ldsO0  = wave * 1024;              // (wave*16)*64
    const int ldsO0b = wave * 1024 + 512;        // (wave*16+8)*64
    const int ldsO1  = 8192 + wave * 1024;       // (128+wave*16)*64
    const int ldsO1b = 8192 + wave * 1024 + 512;

    auto gl = [&](const unsigned short* g, unsigned short* l) {
        __builtin_amdgcn_global_load_lds(
            (const __attribute__((address_space(1))) void*)g,
            (__attribute__((address_space(3))) void*)l, 16, 0, 0);
    };
    auto CH0 = [&](int nb) { gl(pA0, &sA[nb][ldsO0]); gl(pA0b, &sA[nb][ldsO0b]); pA0 += 64; pA0b += 64; };
    auto CH1 = [&](int nb) { gl(pA1, &sA[nb][ldsO1]); gl(pA1b, &sA[nb][ldsO1b]); pA1 += 64; pA1b += 64; };
    auto CH2 = [&](int nb) { gl(pB0, &sB[nb][ldsO0]); gl(pB0b, &sB[nb][ldsO0b]); pB0 += 64; pB0b += 64; };
    auto CH3 = [&](int nb) { gl(pB1, &sB[nb][ldsO1]); gl(pB1b, &sB[nb][ldsO1b]); pB1 += 64; pB1b += 64; };

    // read swizzle: logical chunk (ks*4+quad) of row r at slot ^(r&7); r&7==m&7.
    auto rdA = [&](const unsigned short* buf, int i, int ks) {
        return *(const bf16x8*)&buf[(wr * 128 + i * 16 + m) * 64
                                    + (((ks * 4 + quad) ^ (m & 7)) * 8)];
    };
    auto rdB = [&](const unsigned short* buf, int j, int ks) {
        return *(const bf16x8*)&buf[(wc * 64 + j * 16 + m) * 64
                                    + (((ks * 4 + quad) ^ (m & 7)) * 8)];
    };

    floatx4 acc[8][4];
#pragma unroll
    for (int i = 0; i < 8; i++)
#pragma unroll
        for (int j = 0; j < 4; j++) acc[i][j] = (floatx4)0.f;

    // prologue: stage tile 0 fully (8 instr/wave in flight)
    CH0(0); CH1(0); CH2(0); CH3(0);

#define PHASE_TAIL(I0, CHX)                                                   \
    {                                                                         \
        bf16x8 aA0 = rdA(bufA, (I0), 0),     aA1 = rdA(bufA, (I0), 1);        \
        bf16x8 aB0 = rdA(bufA, (I0) + 1, 0), aB1 = rdA(bufA, (I0) + 1, 1);    \
        if (pf) CHX(nb);                                                      \
        __builtin_amdgcn_s_barrier();                                         \
        __builtin_amdgcn_s_setprio(1);                                        \
        _Pragma("unroll")                                                     \
        for (int j = 0; j < 4; j++) {                                         \
            acc[(I0)][j]     = mfma16(aA0, bfr[j][0], acc[(I0)][j]);          \
            acc[(I0)][j]     = mfma16(aA1, bfr[j][1], acc[(I0)][j]);          \
            acc[(I0) + 1][j] = mfma16(aB0, bfr[j][0], acc[(I0) + 1][j]);      \
            acc[(I0) + 1][j] = mfma16(aB1, bfr[j][1], acc[(I0) + 1][j]);      \
        }                                                                     \
        __builtin_amdgcn_s_setprio(0);                                        \
        __builtin_amdgcn_s_barrier();                                         \
    }

    for (int t = 0; t < 24; ++t) {
        const int cb = t & 1, nb = cb ^ 1;
        const unsigned short* bufA = sA[cb];
        const unsigned short* bufB = sB[cb];
        const bool pf = (t < 23);

        // ---- phase 0: counted-vmcnt wait for tile t, issue t+1 chunk 0
        if (pf) {
            CH0(nb);
            asm volatile("s_waitcnt vmcnt(2)" ::: "memory");
        } else {
            asm volatile("s_waitcnt vmcnt(0)" ::: "memory");
        }
        __builtin_amdgcn_sched_barrier(0);
        __builtin_amdgcn_s_barrier();            // all waves' tile-t loads landed

        bf16x8 bfr[4][2];
#pragma unroll
        for (int j = 0; j < 4; j++) {
            bfr[j][0] = rdB(bufB, j, 0);
            bfr[j][1] = rdB(bufB, j, 1);
        }
        {
            bf16x8 aA0 = rdA(bufA, 0, 0), aA1 = rdA(bufA, 0, 1);
            bf16x8 aB0 = rdA(bufA, 1, 0), aB1 = rdA(bufA, 1, 1);
            __builtin_amdgcn_s_setprio(1);
#pragma unroll
            for (int j = 0; j < 4; j++) {
                acc[0][j] = mfma16(aA0, bfr[j][0], acc[0][j]);
                acc[0][j] = mfma16(aA1, bfr[j][1], acc[0][j]);
                acc[1][j] = mfma16(aB0, bfr[j][0], acc[1][j]);
                acc[1][j] = mfma16(aB1, bfr[j][1], acc[1][j]);
            }
            __builtin_amdgcn_s_setprio(0);
            __builtin_amdgcn_s_barrier();
        }

        // ---- phases 1..3
        PHASE_TAIL(2, CH1)
        PHASE_TAIL(4, CH2)
        PHASE_TAIL(6, CH3)
    }
#undef PHASE_TAIL

    // epilogue: bias + leaky-relu + store (f32, coalesced over m)
    float tb[4];
#pragma unroll
    for (int j = 0; j < 4; j++) tb[j] = t2[oc0 + wc * 64 + j * 16 + m];
#pragma unroll
    for (int i = 0; i < 8; i++) {
#pragma unroll
        for (int r = 0; r < 4; r++) {
            long n = n0 + wr * 128 + i * 16 + quad * 4 + r;
            float* orow = out + n * 768 + oc0 + wc * 64 + m;
#pragma unroll
            for (int j = 0; j < 4; j++) {
                float v = acc[i][j][r] + tb[j];
                orow[j * 16] = v >= 0.f ? v : SLOPE * v;
            }
        }
    }
}

// ---------------------------------------------------------------------------
extern "C" void kernel_launch(void* const* d_in, const int* in_sizes, int n_in,
                              void* d_out, int out_size, void* d_ws, size_t ws_size,
                              hipStream_t stream)
{
    const float* x      = (const float*)d_in[0];
    const float* stem_w = (const float*)d_in[1];
    const float* stem_b = (const float*)d_in[2];
    const float* bn1_g  = (const float*)d_in[3];
    const float* bn1_b  = (const float*)d_in[4];
    const float* bn1_m  = (const float*)d_in[5];
    const float* bn1_v  = (const float*)d_in[6];
    const float* off_w  = (const float*)d_in[7];
    const float* off_b  = (const float*)d_in[8];
    const float* dcn_w  = (const float*)d_in[9];
    const float* dcn_b  = (const float*)d_in[10];
    const float* bn2_g  = (const float*)d_in[11];
    const float* bn2_b  = (const float*)d_in[12];
    const float* bn2_m  = (const float*)d_in[13];
    const float* bn2_v  = (const float*)d_in[14];

    float* ws  = (float*)d_ws;        // needs 81.2 MB
    float* out = (float*)d_out;

    unsigned short* h1  = (unsigned short*)(ws + WS_H1B);
    float* off = ws + WS_OFF;
    float* s1  = ws + WS_S1;
    float* t1  = ws + WS_T1;
    float* t2  = ws + WS_T2;
    unsigned short* Sb  = (unsigned short*)(ws + WS_SB);
    unsigned short* Wtb = (unsigned short*)(ws + WS_WTB);
    unsigned short* Wob = (unsigned short*)(ws + WS_WOB);
    unsigned short* W1b = (unsigned short*)(ws + WS_W1B);

    k0_prep<<<801, 256, 0, stream>>>(stem_w, stem_b, bn1_g, bn1_b, bn1_m, bn1_v,
                                     off_w, dcn_w, dcn_b, bn2_g, bn2_b, bn2_m,
                                     bn2_v, ws);
    // zero the atomic-accumulated offset buffer (re-poisoned 0xAA each launch)
    hipMemsetAsync(off, 0, 401408 * sizeof(float), stream);
    k1_stem_mfma<<<1568, 256, 0, stream>>>(x, W1b, s1, t1, h1);
    k2_mfma<<<392, 256, 0, stream>>>(h1, Wob, off_b, off);
    k3_sample<<<dim3(196, 64), 384, 0, stream>>>(h1, off, Sb);
    k4_gemm_mfma<<<147, 512, 0, stream>>>(Sb, Wtb, t2, out);
}

// Round 5
// 203.913 us; speedup vs baseline: 1.1391x; 1.0454x over previous
//
#include <hip/hip_runtime.h>

#define EPS   1e-5f
#define SLOPE 0.01f

// ---------------------------------------------------------------------------
// Workspace layout (float offsets). Total 20,287,424 floats = 81.1 MB.
// ---------------------------------------------------------------------------
#define WS_H1B  0L            // h1  bf16 NHWC (64,56,56,96)   (9633792 f)
#define WS_OFF  9633792L      // off f32 [n=12544][32]            401408
#define WS_S1   10035200L     // bn1 scale f32 [96]
#define WS_T1   10035296L     // bn1 bias  f32 [96]
#define WS_T2   10035392L     // fused dcn_b+bn2 bias f32 [768]
#define WS_SB   10036160L     // S   bf16 [n=12544][k=1536]    (9633792 f)
#define WS_WTB  19669952L     // Wtb bf16 [oc=768][k=1536]      (589824 f)
#define WS_WOB  20259776L     // Wob bf16 [oc=32][k=1536]        (24576 f)
#define WS_W1B  20284352L     // W1b bf16 [ks=2][oc=96][kl=32]    (3072 f)

__device__ __forceinline__ unsigned short f2bf(float f) {
    unsigned int u = __builtin_bit_cast(unsigned int, f);
    u += 0x7fffu + ((u >> 16) & 1u);
    return (unsigned short)(u >> 16);
}
__device__ __forceinline__ float bf2f(unsigned short u) {
    unsigned int t = ((unsigned int)u) << 16;
    return __builtin_bit_cast(float, t);
}

typedef __attribute__((ext_vector_type(4))) unsigned short ushort4v;
typedef __attribute__((ext_vector_type(8))) unsigned short ushort8v;
typedef __attribute__((ext_vector_type(8))) short bf16x8;
typedef __attribute__((ext_vector_type(4))) float floatx4;

__device__ __forceinline__ floatx4 mfma16(bf16x8 a, bf16x8 b, floatx4 c) {
    return __builtin_amdgcn_mfma_f32_16x16x32_bf16(a, b, c, 0, 0, 0);
}

// LDS pointer type (32-bit AS3) + inline-asm ds_read_b128 the compiler's
// alias analysis can't see (so it cannot insert its own vmcnt drains --
// ordering is handled by OUR vmcnt/lgkmcnt asm + barriers; rule #18).
typedef __attribute__((address_space(3))) unsigned short lds_us;
__device__ __forceinline__ bf16x8 ldsr(const lds_us* p) {
    bf16x8 r;
    asm volatile("ds_read_b128 %0, %1" : "=&v"(r) : "v"(p));
    return r;
}

// ---------------------------------------------------------------------------
// K0: weight prep, transpose-via-LDS for coalescing.
// ---------------------------------------------------------------------------
__global__ __launch_bounds__(256) void k0_prep(
    const float* __restrict__ stem_w, const float* __restrict__ stem_b,
    const float* __restrict__ bn1_g,  const float* __restrict__ bn1_b,
    const float* __restrict__ bn1_m,  const float* __restrict__ bn1_v,
    const float* __restrict__ off_w,  const float* __restrict__ dcn_w,
    const float* __restrict__ dcn_b,  const float* __restrict__ bn2_g,
    const float* __restrict__ bn2_b,  const float* __restrict__ bn2_m,
    const float* __restrict__ bn2_v,  float* __restrict__ ws)
{
    const int tid = threadIdx.x;
    const int blk = blockIdx.x;
    unsigned short* Wtb = (unsigned short*)(ws + WS_WTB);
    unsigned short* Wob = (unsigned short*)(ws + WS_WOB);
    unsigned short* W1b = (unsigned short*)(ws + WS_W1B);

    if (blk < 800) {
        __shared__ float row[1536];
        const int oc = (blk < 768) ? blk : blk - 768;
        const float* src = (blk < 768) ? (dcn_w + (long)oc * 1536)
                                       : (off_w + (long)oc * 1536);
        for (int i = tid; i < 1536; i += 256) row[i] = src[i];
        float sc = 1.f;
        if (blk < 768) sc = bn2_g[oc] * rsqrtf(bn2_v[oc] + EPS);
        __syncthreads();
        if (tid < 192) {
            int k0 = tid * 8;
            ushort8v o;
#pragma unroll
            for (int t = 0; t < 8; t++) {
                int k = k0 + t;
                int kk = k / 96, c = k % 96;      // k = kk*96 + c
                ((unsigned short*)&o)[t] = f2bf(row[c * 16 + kk] * sc);
            }
            unsigned short* dst = (blk < 768) ? (Wtb + (long)oc * 1536 + k0)
                                              : (Wob + (long)oc * 1536 + k0);
            *(ushort8v*)dst = o;
        }
    } else {
        for (int i = tid; i < 6144; i += 256) {
            int ks = i / 3072, rr = i % 3072;
            int oc = rr >> 5, kl = rr & 31;
            int k = ks * 32 + kl;
            W1b[i] = f2bf(k < 48 ? stem_w[oc * 48 + k] : 0.f);
        }
        if (tid < 96) {
            float s = bn1_g[tid] * rsqrtf(bn1_v[tid] + EPS);
            ws[WS_S1 + tid] = s;
            ws[WS_T1 + tid] = stem_b[tid] * s + bn1_b[tid] - bn1_m[tid] * s;
        }
        for (int i = tid; i < 768; i += 256) {
            float inv2 = bn2_g[i] * rsqrtf(bn2_v[i] + EPS);
            ws[WS_T2 + i] = dcn_b[i] * inv2 + bn2_b[i] - bn2_m[i] * inv2;
        }
    }
}

// ---------------------------------------------------------------------------
// K1: stem conv as bf16 MFMA GEMM, coalesced staging + LDS-repacked stores.
// ---------------------------------------------------------------------------
__global__ __launch_bounds__(256) void k1_stem_mfma(
    const float* __restrict__ x, const unsigned short* __restrict__ W1b,
    const float* __restrict__ s1, const float* __restrict__ t1,
    unsigned short* __restrict__ h1)
{
    const int tid  = threadIdx.x;
    const int wave = tid >> 6, lane = tid & 63;
    const int m = lane & 15, quad = lane >> 4;
    const int p0 = blockIdx.x * 128;

    __shared__ unsigned short sm[14336];   // 28672 B
    unsigned short* sA = sm;               // [2][128][32]
    unsigned short* sB = sm + 8192;        // [2][96][32]

#pragma unroll
    for (int i = 0; i < 3; i++) {
        int inst = wave * 3 + i;
        const unsigned short* g = W1b + inst * 512 + lane * 8;
        __builtin_amdgcn_global_load_lds(
            (const __attribute__((address_space(1))) void*)g,
            (__attribute__((address_space(3))) void*)(sB + inst * 512), 16, 0, 0);
    }
    {
        int r = tid >> 1, off = 16 + (tid & 1) * 8;
        *(ushort8v*)&sA[4096 + r * 32 + off] = (ushort8v)0;
    }
#pragma unroll
    for (int i = 0; i < 6; i++) {
        int unit = i * 256 + tid;
        int r = unit & 127, s = unit >> 7;
        int ci = s >> 2, kh = s & 3;
        int p = p0 + r;
        int b = p / 3136, rem = p % 3136;
        int oy = rem / 56, ox = rem % 56;
        float4 v = *(const float4*)&x[((long)((b * 3 + ci) * 224 + oy * 4 + kh)) * 224 + ox * 4];
        ushort4v hv;
        hv.x = f2bf(v.x); hv.y = f2bf(v.y); hv.z = f2bf(v.z); hv.w = f2bf(v.w);
        int k0i = ci * 16 + kh * 4;
        *(ushort4v*)&sA[(k0i >> 5) * 4096 + r * 32 + (k0i & 31)] = hv;
    }
    __syncthreads();

    bf16x8 bfv[6][2], af[2][2];
#pragma unroll
    for (int j = 0; j < 6; j++)
#pragma unroll
        for (int ks = 0; ks < 2; ks++)
            bfv[j][ks] = *(const bf16x8*)&sB[ks * 3072 + (j * 16 + m) * 32 + quad * 8];
#pragma unroll
    for (int rt = 0; rt < 2; rt++)
#pragma unroll
        for (int ks = 0; ks < 2; ks++)
            af[rt][ks] = *(const bf16x8*)&sA[ks * 4096 + (wave * 32 + rt * 16 + m) * 32 + quad * 8];

    floatx4 acc[2][6];
#pragma unroll
    for (int rt = 0; rt < 2; rt++)
#pragma unroll
        for (int j = 0; j < 6; j++) {
            floatx4 a = (floatx4)0.f;
            a = __builtin_amdgcn_mfma_f32_16x16x32_bf16(af[rt][0], bfv[j][0], a, 0, 0, 0);
            a = __builtin_amdgcn_mfma_f32_16x16x32_bf16(af[rt][1], bfv[j][1], a, 0, 0, 0);
            acc[rt][j] = a;
        }

    __syncthreads();
#pragma unroll
    for (int j = 0; j < 6; j++) {
        int c = j * 16 + m;
        float sc = s1[c], bi = t1[c];
#pragma unroll
        for (int rt = 0; rt < 2; rt++)
#pragma unroll
            for (int r = 0; r < 4; r++) {
                int row = wave * 32 + rt * 16 + quad * 4 + r;
                float v = acc[rt][j][r] * sc + bi;
                v = v >= 0.f ? v : SLOPE * v;
                sm[row * 96 + c] = f2bf(v);
            }
    }
    __syncthreads();
#pragma unroll
    for (int i = 0; i < 6; i++) {
        int idx = (i * 256 + tid) * 8;
        *(ushort8v*)&h1[(long)p0 * 96 + idx] = *(const ushort8v*)&sm[idx];
    }
}

// ---------------------------------------------------------------------------
// K2: offset conv, K-split x4 across blocks + dbuf prefetch + atomic reduce.
// ---------------------------------------------------------------------------
__global__ __launch_bounds__(256) void k2_mfma(
    const unsigned short* __restrict__ h1,   // bf16 NHWC
    const unsigned short* __restrict__ Wob,  // [32][1536] bf16
    const float* __restrict__ off_b, float* __restrict__ off)
{
    const int tid  = threadIdx.x;
    const int wave = tid >> 6, lane = tid & 63;
    const int m = lane & 15, quad = lane >> 4;
    const int nt = blockIdx.x % 98, ks = blockIdx.x / 98;
    const int n0 = nt * 128;

    __shared__ unsigned short sA[2][4096];   // [buf][128*32]
    __shared__ unsigned short sB[2][1024];   // [buf][32*32]

    const int skoff = (lane & 3) * 8;
    int n_a = n0 + wave * 32 + (lane >> 2);
    int n_b = n_a + 16;
    int ba = n_a / 196, pa = n_a % 196;
    int bb = n_b / 196, pb = n_b % 196;
    long pixa = ((long)(ba * 56 + (pa / 14) * 4) * 56 + (pa % 14) * 4);
    long pixb = ((long)(bb * 56 + (pb / 14) * 4) * 56 + (pb % 14) * 4);

    const unsigned short* gB = Wob + (long)(wave * 16 + (lane >> 2)) * 1536 + ks * 384 + skoff;
    const int lofA0 = (wave * 32) * 32;
    const int lofA1 = (wave * 32 + 16) * 32;
    const int lofB  = (wave * 16) * 32;

    auto issue = [&](int buf, int kt) {
        int khw = ks * 4 + kt / 3;
        int c0  = (kt % 3) * 32;
        int kh  = khw >> 2, kw = khw & 3;
        long eoff = (long)(kh * 56 + kw) * 96 + c0 + skoff;
        __builtin_amdgcn_global_load_lds(
            (const __attribute__((address_space(1))) void*)(h1 + pixa * 96 + eoff),
            (__attribute__((address_space(3))) void*)&sA[buf][lofA0], 16, 0, 0);
        __builtin_amdgcn_global_load_lds(
            (const __attribute__((address_space(1))) void*)(h1 + pixb * 96 + eoff),
            (__attribute__((address_space(3))) void*)&sA[buf][lofA1], 16, 0, 0);
        if (wave < 2)
            __builtin_amdgcn_global_load_lds(
                (const __attribute__((address_space(1))) void*)(gB + kt * 32),
                (__attribute__((address_space(3))) void*)&sB[buf][lofB], 16, 0, 0);
    };

    floatx4 acc[2][2];
#pragma unroll
    for (int i = 0; i < 2; i++)
#pragma unroll
        for (int j = 0; j < 2; j++) acc[i][j] = (floatx4)0.f;

    issue(0, 0);
    for (int kt = 0; kt < 12; ++kt) {
        __syncthreads();                       // drains tile kt's loads
        if (kt < 11) issue((kt + 1) & 1, kt + 1);
        const unsigned short* bufA = sA[kt & 1];
        const unsigned short* bufB = sB[kt & 1];
        bf16x8 af[2], bfr[2];
#pragma unroll
        for (int i = 0; i < 2; i++)
            af[i] = *(const bf16x8*)&bufA[(wave * 32 + i * 16 + m) * 32 + quad * 8];
#pragma unroll
        for (int j = 0; j < 2; j++)
            bfr[j] = *(const bf16x8*)&bufB[(j * 16 + m) * 32 + quad * 8];
#pragma unroll
        for (int i = 0; i < 2; i++)
#pragma unroll
            for (int j = 0; j < 2; j++)
                acc[i][j] = __builtin_amdgcn_mfma_f32_16x16x32_bf16(
                    af[i], bfr[j], acc[i][j], 0, 0, 0);
    }

    float tb[2];
#pragma unroll
    for (int j = 0; j < 2; j++) tb[j] = (ks == 0) ? off_b[j * 16 + m] : 0.f;
#pragma unroll
    for (int i = 0; i < 2; i++)
#pragma unroll
        for (int r = 0; r < 4; r++) {
            long n = n0 + wave * 32 + i * 16 + quad * 4 + r;
#pragma unroll
            for (int j = 0; j < 2; j++)
                atomicAdd(&off[n * 32 + j * 16 + m], acc[i][j][r] + tb[j]);
        }
}

// ---------------------------------------------------------------------------
// K3: bilinear sampling from bf16 h1 -> S bf16 [n][k], k = kk*96 + c.
// ---------------------------------------------------------------------------
__global__ __launch_bounds__(384) void k3_sample(
    const unsigned short* __restrict__ h1, const float* __restrict__ off,
    unsigned short* __restrict__ S)
{
    const int p = blockIdx.x;     // 0..195
    const int b = blockIdx.y;     // 0..63
    const int y = p / 14, xo = p % 14;
    const int tid = threadIdx.x;
    const int c4 = tid % 24, kk = tid / 24;
    const int kh = kk >> 2, kw = kk & 3;

    const float* ob = off + ((long)(b * 196 + p)) * 32;
    float dy = ob[kk * 2];
    float dx = ob[kk * 2 + 1];

    float py = (float)(y * 4 + kh) + dy;
    float px = (float)(xo * 4 + kw) + dx;
    float y0f = floorf(py), x0f = floorf(px);
    float wy = py - y0f, wx = px - x0f;
    int y0 = (int)y0f, x0 = (int)x0f;
    int y1 = y0 + 1,  x1 = x0 + 1;

    float my0 = (y0 >= 0 && y0 < 56) ? 1.f : 0.f;
    float my1 = (y1 >= 0 && y1 < 56) ? 1.f : 0.f;
    float mx0 = (x0 >= 0 && x0 < 56) ? 1.f : 0.f;
    float mx1 = (x1 >= 0 && x1 < 56) ? 1.f : 0.f;
    int y0c = min(max(y0, 0), 55), y1c = min(max(y1, 0), 55);
    int x0c = min(max(x0, 0), 55), x1c = min(max(x1, 0), 55);

    const unsigned short* hb = h1 + (long)b * 56 * 56 * 96 + c4 * 4;
    ushort4v v00 = *(const ushort4v*)&hb[(y0c * 56 + x0c) * 96];
    ushort4v v01 = *(const ushort4v*)&hb[(y0c * 56 + x1c) * 96];
    ushort4v v10 = *(const ushort4v*)&hb[(y1c * 56 + x0c) * 96];
    ushort4v v11 = *(const ushort4v*)&hb[(y1c * 56 + x1c) * 96];

    float w00 = my0 * mx0 * (1.f - wy) * (1.f - wx);
    float w01 = my0 * mx1 * (1.f - wy) * wx;
    float w10 = my1 * mx0 * wy * (1.f - wx);
    float w11 = my1 * mx1 * wy * wx;

    ushort4v rr;
#pragma unroll
    for (int c = 0; c < 4; c++) {
        float v = bf2f(((unsigned short*)&v00)[c]) * w00
                + bf2f(((unsigned short*)&v01)[c]) * w01
                + bf2f(((unsigned short*)&v10)[c]) * w10
                + bf2f(((unsigned short*)&v11)[c]) * w11;
        ((unsigned short*)&rr)[c] = f2bf(v);
    }

    long n = (long)b * 196 + p;
    *(ushort4v*)&S[n * 1536 + kk * 96 + c4 * 4] = rr;
}

// ---------------------------------------------------------------------------
// K4: bf16 MFMA GEMM  C[n][oc] = S[n][k] * Wtb[oc][k]^T  (N=12544,M=768,K=1536)
// Same geometry/schedule as r4 (BM=BN=256, BK=64, 8 waves, 4 phases/K-tile,
// counted vmcnt(2), 147 blocks XCD-grouped) with ONE change: all K-loop
// ds_read_b128 are INLINE ASM. Theory: hipcc's alias analysis can't prove
// sA[cb] reads disjoint from sA[nb] gload_lds writes -> it inserted its own
// s_waitcnt vmcnt(0) before the LDS reads, re-creating the drain-per-phase
// stall in every previous round (invariant ~17% MfmaUtil across 4 different
// schedules). Asm reads are invisible to the compiler's memory model; RAW/WAR
// ordering is OURS: per-wave vmcnt(2)+barrier (stage->read), lgkmcnt(0) +
// sched_barrier(0) before MFMA (rule #18), end-barrier before next overwrite.
// ---------------------------------------------------------------------------
__global__ __launch_bounds__(512, 2) void k4_gemm_mfma(
    const unsigned short* __restrict__ S,    // [12544][1536] bf16
    const unsigned short* __restrict__ Wtb,  // [768][1536]  bf16 (B^T, scaled)
    const float* __restrict__ t2, float* __restrict__ out)
{
    const int tid  = threadIdx.x;
    const int wave = tid >> 6, lane = tid & 63;

    // bijective XCD grouping for nwg=147: q=18, r=3
    int b = blockIdx.x;
    int xcd = b & 7, pos = b >> 3;
    int work = ((xcd < 3) ? xcd * 19 : 57 + (xcd - 3) * 18) + pos;
    const int n0  = (work / 3) * 256;
    const int oc0 = (work % 3) * 256;

    const int wr = wave >> 2, wc = wave & 3;     // 2 x 4 wave grid
    const int m = lane & 15, quad = lane >> 4;

    __shared__ unsigned short sA[2][16384];      // [buf][256 rows * 64 k] 64KB
    __shared__ unsigned short sB[2][16384];      // [buf][256 rows * 64 k] 64KB

    // staging: one gload_lds = 64 lanes x 16B = 8 rows of 128B.
    // lane -> row lr = lane>>3, slot ls = lane&7; LDS slot s of row r holds
    // logical k-chunk s^(r&7); source fetches chunk ls^lr.
    const int lr = lane >> 3;
    const int ls = lane & 7;
    const int swzk = ((ls ^ lr) * 8);            // element offset in 64-k row

    const unsigned short* pA0  = S   + (long)(n0  + wave * 16 + lr) * 1536 + swzk;
    const unsigned short* pA0b = pA0 + 8 * 1536;
    const unsigned short* pA1  = pA0 + 128 * 1536;
    const unsigned short* pA1b = pA1 + 8 * 1536;
    const unsigned short* pB0  = Wtb + (long)(oc0 + wave * 16 + lr) * 1536 + swzk;
    const unsigned short* pB0b = pB0 + 8 * 1536;
    const unsigned short* pB1  = pB0 + 128 * 1536;
    const unsigned short* pB1b = pB1 + 8 * 1536;

    const int ldsO0  = wave * 1024;              // (wave*16)*64
    const int ldsO0b = wave * 1024 + 512;        // (wave*16+8)*64
    const int ldsO1  = 8192 + wave * 1024;       // (128+wave*16)*64
    const int ldsO1b = 8192 + wave * 1024 + 512;

    auto gl = [&](const unsigned short* g, unsigned short* l) {
        __builtin_amdgcn_global_load_lds(
            (const __attribute__((address_space(1))) void*)g,
            (__attribute__((address_space(3))) void*)l, 16, 0, 0);
    };
    auto CH0 = [&](int nb) { gl(pA0, &sA[nb][ldsO0]); gl(pA0b, &sA[nb][ldsO0b]); pA0 += 64; pA0b += 64; };
    auto CH1 = [&](int nb) { gl(pA1, &sA[nb][ldsO1]); gl(pA1b, &sA[nb][ldsO1b]); pA1 += 64; pA1b += 64; };
    auto CH2 = [&](int nb) { gl(pB0, &sB[nb][ldsO0]); gl(pB0b, &sB[nb][ldsO0b]); pB0 += 64; pB0b += 64; };
    auto CH3 = [&](int nb) { gl(pB1, &sB[nb][ldsO1]); gl(pB1b, &sB[nb][ldsO1b]); pB1 += 64; pB1b += 64; };

    // per-thread fragment addressing (swizzled read): logical chunk
    // (ks*4+quad) of row r lives at slot ^(r&7); r&7 == m&7.
    const int rowA = (wr * 128 + m) * 64;
    const int rowB = (wc * 64 + m) * 64;
    const int x0 = ((quad)     ^ (m & 7)) * 8;   // ks = 0
    const int x1 = ((quad + 4) ^ (m & 7)) * 8;   // ks = 1

    floatx4 acc[8][4];
#pragma unroll
    for (int i = 0; i < 8; i++)
#pragma unroll
        for (int j = 0; j < 4; j++) acc[i][j] = (floatx4)0.f;

    // prologue: stage tile 0 fully (8 instr/wave in flight)
    CH0(0); CH1(0); CH2(0); CH3(0);

#define MFMA_PHASE(I0, A00, A01, A10, A11)                                    \
    __builtin_amdgcn_s_setprio(1);                                            \
    _Pragma("unroll")                                                         \
    for (int j = 0; j < 4; j++) {                                             \
        acc[(I0)][j]     = mfma16(A00, bfr[j][0], acc[(I0)][j]);              \
        acc[(I0) + 1][j] = mfma16(A10, bfr[j][0], acc[(I0) + 1][j]);          \
        acc[(I0)][j]     = mfma16(A01, bfr[j][1], acc[(I0)][j]);              \
        acc[(I0) + 1][j] = mfma16(A11, bfr[j][1], acc[(I0) + 1][j]);          \
    }                                                                         \
    __builtin_amdgcn_s_setprio(0);

    for (int t = 0; t < 24; ++t) {
        const int cb = t & 1, nb = cb ^ 1;
        const bool pf = (t < 23);
        const lds_us* pAk0 = (const lds_us*)(sA[cb]) + rowA + x0;
        const lds_us* pAk1 = (const lds_us*)(sA[cb]) + rowA + x1;
        const lds_us* pBk0 = (const lds_us*)(sB[cb]) + rowB + x0;
        const lds_us* pBk1 = (const lds_us*)(sB[cb]) + rowB + x1;

        // ---- phase 0: counted-vmcnt wait for tile t, issue t+1 chunk 0
        if (pf) {
            CH0(nb);
            asm volatile("s_waitcnt vmcnt(2)" ::: "memory");
        } else {
            asm volatile("s_waitcnt vmcnt(0)" ::: "memory");
        }
        __builtin_amdgcn_sched_barrier(0);
        __builtin_amdgcn_s_barrier();            // all waves' tile-t loads landed

        bf16x8 bfr[4][2];
#pragma unroll
        for (int j = 0; j < 4; j++) {
            bfr[j][0] = ldsr(pBk0 + j * 1024);
            bfr[j][1] = ldsr(pBk1 + j * 1024);
        }
        bf16x8 a00 = ldsr(pAk0);
        bf16x8 a01 = ldsr(pAk1);
        bf16x8 a10 = ldsr(pAk0 + 1024);
        bf16x8 a11 = ldsr(pAk1 + 1024);
        asm volatile("s_waitcnt lgkmcnt(0)" ::: "memory");
        __builtin_amdgcn_sched_barrier(0);
        MFMA_PHASE(0, a00, a01, a10, a11)
        __builtin_amdgcn_s_barrier();

        // ---- phase 1 (i=2,3), prefetch chunk 1
        a00 = ldsr(pAk0 + 2 * 1024);
        a01 = ldsr(pAk1 + 2 * 1024);
        a10 = ldsr(pAk0 + 3 * 1024);
        a11 = ldsr(pAk1 + 3 * 1024);
        if (pf) CH1(nb);
        __builtin_amdgcn_s_barrier();
        asm volatile("s_waitcnt lgkmcnt(0)" ::: "memory");
        __builtin_amdgcn_sched_barrier(0);
        MFMA_PHASE(2, a00, a01, a10, a11)
        __builtin_amdgcn_s_barrier();

        // ---- phase 2 (i=4,5), prefetch chunk 2
        a00 = ldsr(pAk0 + 4 * 1024);
        a01 = ldsr(pAk1 + 4 * 1024);
        a10 = ldsr(pAk0 + 5 * 1024);
        a11 = ldsr(pAk1 + 5 * 1024);
        if (pf) CH2(nb);
        __builtin_amdgcn_s_barrier();
        asm volatile("s_waitcnt lgkmcnt(0)" ::: "memory");
        __builtin_amdgcn_sched_barrier(0);
        MFMA_PHASE(4, a00, a01, a10, a11)
        __builtin_amdgcn_s_barrier();

        // ---- phase 3 (i=6,7), prefetch chunk 3
        a00 = ldsr(pAk0 + 6 * 1024);
        a01 = ldsr(pAk1 + 6 * 1024);
        a10 = ldsr(pAk0 + 7 * 1024);
        a11 = ldsr(pAk1 + 7 * 1024);
        if (pf) CH3(nb);
        __builtin_amdgcn_s_barrier();
        asm volatile("s_waitcnt lgkmcnt(0)" ::: "memory");
        __builtin_amdgcn_sched_barrier(0);
        MFMA_PHASE(6, a00, a01, a10, a11)
        __builtin_amdgcn_s_barrier();
    }
#undef MFMA_PHASE

    // epilogue: bias + leaky-relu + store (f32, coalesced over m)
    float tb[4];
#pragma unroll
    for (int j = 0; j < 4; j++) tb[j] = t2[oc0 + wc * 64 + j * 16 + m];
#pragma unroll
    for (int i = 0; i < 8; i++) {
#pragma unroll
        for (int r = 0; r < 4; r++) {
            long n = n0 + wr * 128 + i * 16 + quad * 4 + r;
            float* orow = out + n * 768 + oc0 + wc * 64 + m;
#pragma unroll
            for (int j = 0; j < 4; j++) {
                float v = acc[i][j][r] + tb[j];
                orow[j * 16] = v >= 0.f ? v : SLOPE * v;
            }
        }
    }
}

// ---------------------------------------------------------------------------
extern "C" void kernel_launch(void* const* d_in, const int* in_sizes, int n_in,
                              void* d_out, int out_size, void* d_ws, size_t ws_size,
                              hipStream_t stream)
{
    const float* x      = (const float*)d_in[0];
    const float* stem_w = (const float*)d_in[1];
    const float* stem_b = (const float*)d_in[2];
    const float* bn1_g  = (const float*)d_in[3];
    const float* bn1_b  = (const float*)d_in[4];
    const float* bn1_m  = (const float*)d_in[5];
    const float* bn1_v  = (const float*)d_in[6];
    const float* off_w  = (const float*)d_in[7];
    const float* off_b  = (const float*)d_in[8];
    const float* dcn_w  = (const float*)d_in[9];
    const float* dcn_b  = (const float*)d_in[10];
    const float* bn2_g  = (const float*)d_in[11];
    const float* bn2_b  = (const float*)d_in[12];
    const float* bn2_m  = (const float*)d_in[13];
    const float* bn2_v  = (const float*)d_in[14];

    float* ws  = (float*)d_ws;        // needs 81.2 MB
    float* out = (float*)d_out;

    unsigned short* h1  = (unsigned short*)(ws + WS_H1B);
    float* off = ws + WS_OFF;
    float* s1  = ws + WS_S1;
    float* t1  = ws + WS_T1;
    float* t2  = ws + WS_T2;
    unsigned short* Sb  = (unsigned short*)(ws + WS_SB);
    unsigned short* Wtb = (unsigned short*)(ws + WS_WTB);
    unsigned short* Wob = (unsigned short*)(ws + WS_WOB);
    unsigned short* W1b = (unsigned short*)(ws + WS_W1B);

    k0_prep<<<801, 256, 0, stream>>>(stem_w, stem_b, bn1_g, bn1_b, bn1_m, bn1_v,
                                     off_w, dcn_w, dcn_b, bn2_g, bn2_b, bn2_m,
                                     bn2_v, ws);
    // zero the atomic-accumulated offset buffer (re-poisoned 0xAA each launch)
    hipMemsetAsync(off, 0, 401408 * sizeof(float), stream);
    k1_stem_mfma<<<1568, 256, 0, stream>>>(x, W1b, s1, t1, h1);
    k2_mfma<<<392, 256, 0, stream>>>(h1, Wob, off_b, off);
    k3_sample<<<dim3(196, 64), 384, 0, stream>>>(h1, off, Sb);
    k4_gemm_mfma<<<147, 512, 0, stream>>>(Sb, Wtb, t2, out);
}